// Round 5
// baseline (710.871 us; speedup 1.0000x reference)
//
#include <hip/hip_runtime.h>
#include <cstdint>

typedef __attribute__((ext_vector_type(8))) short short8;
typedef __attribute__((ext_vector_type(4))) float floatx4;
typedef __attribute__((ext_vector_type(4))) unsigned short ushort4v;
typedef unsigned short ushort;

#define T_LEN 2048
#define D_DIM 1024
#define HQn 16
#define HKVn 4
#define NE 8
#define FF 2752
#define NTOK 2048
#define NSLOT 4096
#define ATT_SCALE 0.125f
#define GATE_TPB 16

__device__ inline ushort f2bf(float f) {
  union { float f; unsigned int i; } v; v.f = f;
  unsigned int r = v.i + 0x7fffu + ((v.i >> 16) & 1u);
  return (ushort)(r >> 16);
}
__device__ inline float bf2f(ushort h) {
  union { unsigned int i; float f; } v; v.i = ((unsigned int)h) << 16;
  return v.f;
}
__device__ inline void split8(const float* v, short8& hi, short8& lo) {
#pragma unroll
  for (int i = 0; i < 8; i++) {
    ushort h = f2bf(v[i]);
    hi[i] = (short)h;
    lo[i] = (short)f2bf(v[i] - bf2f(h));
  }
}
__device__ inline floatx4 mfma16(short8 a, short8 b, floatx4 c) {
  return __builtin_amdgcn_mfma_f32_16x16x32_bf16(a, b, c, 0, 0, 0);
}
// async global->LDS, 16B per lane; LDS dest = wave-uniform base + lane*16
#define DMA16(g, l)                                                              \
  __builtin_amdgcn_global_load_lds((const __attribute__((address_space(1))) void*)(g), \
                                   (__attribute__((address_space(3))) void*)(l), 16, 0, 0)

// ---------------- transpose+convert fp32 -> bf16 [C][R] (batch z) ----------------
__global__ __launch_bounds__(256) void k_cvtT(const float* __restrict__ src,
                                              ushort* __restrict__ dst, int R, int C) {
  __shared__ float tile[32][33];
  size_t sb = (size_t)blockIdx.z * R * C;
  const float* s = src + sb;
  ushort* d = dst + sb;
  int r0 = blockIdx.y * 32, c0 = blockIdx.x * 32;
  int tc = threadIdx.x & 31, tr = threadIdx.x >> 5;
#pragma unroll
  for (int i = 0; i < 4; i++)
    tile[tr + i * 8][tc] = s[(size_t)(r0 + tr + i * 8) * C + c0 + tc];
  __syncthreads();
#pragma unroll
  for (int i = 0; i < 4; i++) {
    int cc = tr + i * 8;
    d[(size_t)(c0 + cc) * R + r0 + tc] = f2bf(tile[tc][cc]);
  }
}

// ---------------- transpose+split fp32 -> hi/lo bf16 [C][R] ----------------
__global__ __launch_bounds__(256) void k_cvtT2(const float* __restrict__ src,
                                               ushort* __restrict__ dh,
                                               ushort* __restrict__ dl, int R, int C) {
  __shared__ float tile[32][33];
  int r0 = blockIdx.y * 32, c0 = blockIdx.x * 32;
  int tc = threadIdx.x & 31, tr = threadIdx.x >> 5;
#pragma unroll
  for (int i = 0; i < 4; i++)
    tile[tr + i * 8][tc] = src[(size_t)(r0 + tr + i * 8) * C + c0 + tc];
  __syncthreads();
#pragma unroll
  for (int i = 0; i < 4; i++) {
    int cc = tr + i * 8;
    float v = tile[tc][cc];
    ushort h = f2bf(v);
    dh[(size_t)(c0 + cc) * R + r0 + tc] = h;
    dl[(size_t)(c0 + cc) * R + r0 + tc] = f2bf(v - bf2f(h));
  }
}

// ---------------- RMSNorm fp32 -> hi/lo bf16 split ----------------
__global__ __launch_bounds__(256) void k_rmsnorm2(const float* __restrict__ x,
                                                  const float* __restrict__ g,
                                                  ushort* __restrict__ oh,
                                                  ushort* __restrict__ ol) {
  int row = blockIdx.x;
  int t = threadIdx.x;
  const float4* x4 = (const float4*)(x + (size_t)row * D_DIM);
  float4 v = x4[t];
  float ss = v.x * v.x + v.y * v.y + v.z * v.z + v.w * v.w;
#pragma unroll
  for (int off = 32; off; off >>= 1) ss += __shfl_xor(ss, off, 64);
  __shared__ float red[4];
  if ((t & 63) == 0) red[t >> 6] = ss;
  __syncthreads();
  float tot = red[0] + red[1] + red[2] + red[3];
  float sc = rsqrtf(tot * (1.0f / D_DIM) + 1e-6f);
  const float4* g4 = (const float4*)g;
  float4 gv = g4[t];
  float vals[4] = {v.x * gv.x * sc, v.y * gv.y * sc, v.z * gv.z * sc, v.w * gv.w * sc};
  ushort4v h4, l4;
#pragma unroll
  for (int i = 0; i < 4; i++) {
    ushort h = f2bf(vals[i]);
    h4[i] = h;
    l4[i] = f2bf(vals[i] - bf2f(h));
  }
  *(ushort4v*)(oh + (size_t)row * D_DIM + t * 4) = h4;
  *(ushort4v*)(ol + (size_t)row * D_DIM + t * 4) = l4;
}

// ------- split-bf16 emulated-fp32 MFMA GEMM, 2-phase double-buffered -------
// Block tile 64m x 128n, 4 waves, wave tile 32m x 64n (acc 32 regs).
// LDS per buffer: [Ah 2048][Al 2048][Bh 4096][Bl 4096] ushorts (24 KB), x2 = 48 KB.
// K-loop: stage(t+1 -> other buffer) BEFORE compute(t); ONE barrier per tile.
__global__ __launch_bounds__(256) void k_sgemm(const ushort* __restrict__ Ahg,
                                               const ushort* __restrict__ Alg,
                                               const ushort* __restrict__ Bhg,
                                               const ushort* __restrict__ Blg,
                                               float* __restrict__ C,
                                               const float* __restrict__ res,
                                               int N, int K) {
  __shared__ __align__(16) ushort L0[12288], L1[12288];
  int tid = threadIdx.x;
  int m0 = blockIdx.y * 64, n0 = blockIdx.x * 128;
  int wave = tid >> 6, lane = tid & 63, quad = lane >> 4, l15 = lane & 15;
  int wm = (wave >> 1) * 32, wn = (wave & 1) * 64;
  floatx4 acc[2][4];
#pragma unroll
  for (int i = 0; i < 2; i++)
#pragma unroll
    for (int j = 0; j < 4; j++) acc[i][j] = (floatx4){0.f, 0.f, 0.f, 0.f};
  const ushort* src[6];
  int off[6];
  int srow = lane >> 2;
  int kc = ((lane & 3) ^ ((lane >> 3) & 3)) * 8;
#pragma unroll
  for (int j = 0; j < 6; j++) {
    int c = wave * 6 + j;
    if (c < 4) {
      src[j] = Ahg + (size_t)(m0 + c * 16 + srow) * K + kc;
      off[j] = c * 512;
    } else if (c < 8) {
      src[j] = Alg + (size_t)(m0 + (c - 4) * 16 + srow) * K + kc;
      off[j] = 2048 + (c - 4) * 512;
    } else if (c < 16) {
      src[j] = Bhg + (size_t)(n0 + (c - 8) * 16 + srow) * K + kc;
      off[j] = 4096 + (c - 8) * 512;
    } else {
      src[j] = Blg + (size_t)(n0 + (c - 16) * 16 + srow) * K + kc;
      off[j] = 8192 + (c - 16) * 512;
    }
  }
  auto stage = [&](ushort* Ld, int k0) {
#pragma unroll
    for (int j = 0; j < 6; j++) DMA16(src[j] + k0, Ld + off[j]);
  };
  auto compute = [&](const ushort* Ld) {
    const ushort* Ah = Ld;
    const ushort* Al = Ld + 2048;
    const ushort* Bh = Ld + 4096;
    const ushort* Bl = Ld + 8192;
    short8 ah[2], al[2], bh[4], bl[4];
#pragma unroll
    for (int mt = 0; mt < 2; mt++) {
      int ar = wm + mt * 16 + l15;
      int sw = (quad ^ ((ar >> 1) & 3)) * 8;
      ah[mt] = *(short8*)&Ah[ar * 32 + sw];
      al[mt] = *(short8*)&Al[ar * 32 + sw];
    }
#pragma unroll
    for (int nt = 0; nt < 4; nt++) {
      int br = wn + nt * 16 + l15;
      int sw = (quad ^ ((br >> 1) & 3)) * 8;
      bh[nt] = *(short8*)&Bh[br * 32 + sw];
      bl[nt] = *(short8*)&Bl[br * 32 + sw];
    }
#pragma unroll
    for (int mt = 0; mt < 2; mt++)
#pragma unroll
      for (int nt = 0; nt < 4; nt++) {
        acc[mt][nt] = mfma16(ah[mt], bh[nt], acc[mt][nt]);
        acc[mt][nt] = mfma16(ah[mt], bl[nt], acc[mt][nt]);
        acc[mt][nt] = mfma16(al[mt], bh[nt], acc[mt][nt]);
      }
  };
  int nt = K >> 5;
  stage(L0, 0);
  __syncthreads();
  for (int t = 0; t < nt; t++) {
    if ((t & 1) == 0) {
      if (t + 1 < nt) stage(L1, (t + 1) << 5);
      compute(L0);
    } else {
      if (t + 1 < nt) stage(L0, (t + 1) << 5);
      compute(L1);
    }
    __syncthreads();
  }
#pragma unroll
  for (int mt = 0; mt < 2; mt++) {
    int row = m0 + wm + mt * 16 + quad * 4;
#pragma unroll
    for (int nt2 = 0; nt2 < 4; nt2++) {
      int col = n0 + wn + nt2 * 16 + l15;
#pragma unroll
      for (int r = 0; r < 4; r++) {
        float v = acc[mt][nt2][r];
        if (res) v += res[(size_t)(row + r) * N + col];
        C[(size_t)(row + r) * N + col] = v;
      }
    }
  }
}

// ------- RoPE fp32 -> split-bf16: qkvf [T,1536] -> qhi/qlo [HQ][T][64], khi/klo [HKV][T][64] -------
__global__ __launch_bounds__(256) void k_rope_cvt(const float* __restrict__ qkvf,
                                                  ushort* __restrict__ qhi,
                                                  ushort* __restrict__ qlo,
                                                  ushort* __restrict__ khi,
                                                  ushort* __restrict__ klo) {
  int t = blockIdx.x;
  const float* row = qkvf + (size_t)t * 1536;
  for (int it = threadIdx.x; it < (HQn + HKVn) * 32; it += 256) {
    int hh = it >> 5, i = it & 31;
    float inv = powf(10000.0f, -(float)i / 32.0f);
    float ang = (float)t * inv;
    float c = cosf(ang), s = sinf(ang);
    const float* p;
    ushort *dh, *dl;
    size_t base;
    if (hh < HQn) {
      p = row + hh * 64;
      base = ((size_t)hh * T_LEN + t) * 64;
      dh = qhi; dl = qlo;
    } else {
      int h2 = hh - HQn;
      p = row + 1024 + h2 * 64;
      base = ((size_t)h2 * T_LEN + t) * 64;
      dh = khi; dl = klo;
    }
    float a = p[i], b = p[i + 32];
    float v0 = a * c - b * s;
    float v1 = b * c + a * s;
    ushort h0 = f2bf(v0);
    dh[base + i] = h0;
    dl[base + i] = f2bf(v0 - bf2f(h0));
    ushort h1 = f2bf(v1);
    dh[base + i + 32] = h1;
    dl[base + i + 32] = f2bf(v1 - bf2f(h1));
  }
}

// ------- V transpose fp32 -> split-bf16: qkvf v-part -> vbth/vbtl [HKV*64][T] -------
__global__ __launch_bounds__(256) void k_vT(const float* __restrict__ qkvf,
                                            ushort* __restrict__ vbth,
                                            ushort* __restrict__ vbtl) {
  __shared__ float tile[32][33];
  int t0 = blockIdx.x * 32;
  int dh = blockIdx.y;
  int col0 = 1280 + dh * 32;
  int tc = threadIdx.x & 31, tr = threadIdx.x >> 5;
#pragma unroll
  for (int i = 0; i < 4; i++)
    tile[tr + i * 8][tc] = qkvf[(size_t)(t0 + tr + i * 8) * 1536 + col0 + tc];
  __syncthreads();
#pragma unroll
  for (int i = 0; i < 4; i++) {
    int dd = tr + i * 8;
    float v = tile[tc][dd];
    ushort h = f2bf(v);
    size_t idx = (size_t)(dh * 32 + dd) * T_LEN + t0 + tc;
    vbth[idx] = h;
    vbtl[idx] = f2bf(v - bf2f(h));
  }
}

// ------- split-bf16 MFMA flash attention, DMA-staged K/V, balanced q-tile pairing -------
__global__ __launch_bounds__(256) void k_attn(const ushort* __restrict__ qhi,
                                              const ushort* __restrict__ qlo,
                                              const ushort* __restrict__ khi,
                                              const ushort* __restrict__ klo,
                                              const ushort* __restrict__ vbth,
                                              const ushort* __restrict__ vbtl,
                                              ushort* __restrict__ obh,
                                              ushort* __restrict__ obl) {
  __shared__ __align__(16) ushort Kh[4096], Kl[4096], Vh[4096], Vl[4096];
  __shared__ ushort Psh[4 * 16 * 72], Psl[4 * 16 * 72];
  int qh = blockIdx.y, kvh = qh >> 2;
  int tid = threadIdx.x, wave = tid >> 6, lane = tid & 63;
  int quad = lane >> 4, l15 = lane & 15;
  int sx = l15 >> 1;  // read-side swizzle (row>>1)&7 for rows nt*16+l15
  int rlb = lane >> 3;                      // staging: row-in-8
  int csb = (lane & 7) ^ (lane >> 4);       // staging: source chunk base
#pragma unroll 1
  for (int hf = 0; hf < 2; hf++) {
    int xt = hf ? (31 - (int)blockIdx.x) : (int)blockIdx.x;
    int r0 = xt * 64;
    const ushort* qbh_ = qhi + ((size_t)qh * T_LEN + r0 + wave * 16 + l15) * 64;
    const ushort* qbl_ = qlo + ((size_t)qh * T_LEN + r0 + wave * 16 + l15) * 64;
    short8 aqh0 = *(const short8*)&qbh_[quad * 8];
    short8 aqh1 = *(const short8*)&qbh_[32 + quad * 8];
    short8 aql0 = *(const short8*)&qbl_[quad * 8];
    short8 aql1 = *(const short8*)&qbl_[32 + quad * 8];
    floatx4 oacc[4];
#pragma unroll
    for (int nt = 0; nt < 4; nt++) oacc[nt] = (floatx4){0.f, 0.f, 0.f, 0.f};
    float mrun[4], lrun[4];
#pragma unroll
    for (int r = 0; r < 4; r++) { mrun[r] = -INFINITY; lrun[r] = 0.f; }
    for (int cc = 0; cc <= xt; cc++) {
      __syncthreads();  // all waves done reading previous tile
      if (wave < 2) {
        const ushort* G = (wave == 0) ? khi : klo;
        ushort* L = (wave == 0) ? Kh : Kl;
        size_t rbase = (size_t)kvh * T_LEN + cc * 64;
#pragma unroll
        for (int i = 0; i < 8; i++) {
          int ch = csb ^ ((i & 1) * 4);
          DMA16(G + (rbase + i * 8 + rlb) * 64 + ch * 8, L + i * 512);
        }
      } else {
        const ushort* G = (wave == 2) ? vbth : vbtl;
        ushort* L = (wave == 2) ? Vh : Vl;
#pragma unroll
        for (int i = 0; i < 8; i++) {
          int ch = csb ^ ((i & 1) * 4);
          DMA16(G + ((size_t)(kvh * 64 + i * 8 + rlb)) * T_LEN + cc * 64 + ch * 8,
                L + i * 512);
        }
      }
      __syncthreads();  // DMA landed (vmcnt drained by barrier)
      floatx4 s[4];
#pragma unroll
      for (int nt = 0; nt < 4; nt++) {
        int row = nt * 16 + l15;
        short8 bh0 = *(short8*)&Kh[row * 64 + (quad ^ sx) * 8];
        short8 bh1 = *(short8*)&Kh[row * 64 + ((4 + quad) ^ sx) * 8];
        short8 bl0 = *(short8*)&Kl[row * 64 + (quad ^ sx) * 8];
        short8 bl1 = *(short8*)&Kl[row * 64 + ((4 + quad) ^ sx) * 8];
        floatx4 z = (floatx4){0.f, 0.f, 0.f, 0.f};
        z = mfma16(aqh0, bh0, z);
        z = mfma16(aqh1, bh1, z);
        z = mfma16(aqh0, bl0, z);
        z = mfma16(aqh1, bl1, z);
        z = mfma16(aql0, bh0, z);
        z = mfma16(aql1, bh1, z);
        s[nt] = z;
      }
      int rowg0 = r0 + wave * 16 + quad * 4;
#pragma unroll
      for (int nt = 0; nt < 4; nt++) {
        int colg = cc * 64 + nt * 16 + l15;
#pragma unroll
        for (int r = 0; r < 4; r++) {
          float v = s[nt][r] * ATT_SCALE;
          s[nt][r] = (colg > rowg0 + r) ? -INFINITY : v;
        }
      }
      float mnew[4], alpha[4], psum[4];
#pragma unroll
      for (int r = 0; r < 4; r++) {
        float mx = fmaxf(fmaxf(s[0][r], s[1][r]), fmaxf(s[2][r], s[3][r]));
#pragma unroll
        for (int off = 1; off < 16; off <<= 1) mx = fmaxf(mx, __shfl_xor(mx, off, 64));
        mnew[r] = fmaxf(mrun[r], mx);
        psum[r] = 0.f;
      }
#pragma unroll
      for (int nt = 0; nt < 4; nt++)
#pragma unroll
        for (int r = 0; r < 4; r++) {
          float p = __expf(s[nt][r] - mnew[r]);
          s[nt][r] = p;
          psum[r] += p;
        }
#pragma unroll
      for (int r = 0; r < 4; r++) {
        float ps = psum[r];
#pragma unroll
        for (int off = 1; off < 16; off <<= 1) ps += __shfl_xor(ps, off, 64);
        alpha[r] = __expf(mrun[r] - mnew[r]);
        lrun[r] = lrun[r] * alpha[r] + ps;
        mrun[r] = mnew[r];
      }
#pragma unroll
      for (int nt = 0; nt < 4; nt++)
#pragma unroll
        for (int r = 0; r < 4; r++) oacc[nt][r] *= alpha[r];
#pragma unroll
      for (int nt = 0; nt < 4; nt++)
#pragma unroll
        for (int r = 0; r < 4; r++) {
          float p = s[nt][r];
          ushort ph = f2bf(p);
          Psh[wave * 1152 + (quad * 4 + r) * 72 + nt * 16 + l15] = ph;
          Psl[wave * 1152 + (quad * 4 + r) * 72 + nt * 16 + l15] = f2bf(p - bf2f(ph));
        }
      short8 aph0 = *(short8*)&Psh[wave * 1152 + l15 * 72 + quad * 8];
      short8 aph1 = *(short8*)&Psh[wave * 1152 + l15 * 72 + 32 + quad * 8];
      short8 apl0 = *(short8*)&Psl[wave * 1152 + l15 * 72 + quad * 8];
      short8 apl1 = *(short8*)&Psl[wave * 1152 + l15 * 72 + 32 + quad * 8];
#pragma unroll
      for (int nt = 0; nt < 4; nt++) {
        int row = nt * 16 + l15;
        short8 bvh0 = *(short8*)&Vh[row * 64 + (quad ^ sx) * 8];
        short8 bvh1 = *(short8*)&Vh[row * 64 + ((4 + quad) ^ sx) * 8];
        short8 bvl0 = *(short8*)&Vl[row * 64 + (quad ^ sx) * 8];
        short8 bvl1 = *(short8*)&Vl[row * 64 + ((4 + quad) ^ sx) * 8];
        oacc[nt] = mfma16(aph0, bvh0, oacc[nt]);
        oacc[nt] = mfma16(aph1, bvh1, oacc[nt]);
        oacc[nt] = mfma16(aph0, bvl0, oacc[nt]);
        oacc[nt] = mfma16(aph1, bvl1, oacc[nt]);
        oacc[nt] = mfma16(apl0, bvh0, oacc[nt]);
        oacc[nt] = mfma16(apl1, bvh1, oacc[nt]);
      }
    }
#pragma unroll
    for (int nt = 0; nt < 4; nt++)
#pragma unroll
      for (int r = 0; r < 4; r++) {
        int rowg = r0 + wave * 16 + quad * 4 + r;
        float v = oacc[nt][r] / lrun[r];
        ushort h = f2bf(v);
        size_t idx = (size_t)rowg * D_DIM + qh * 64 + nt * 16 + l15;
        obh[idx] = h;
        obl[idx] = f2bf(v - bf2f(h));
      }
  }
}

// ------- gate: fp32 rmsnorm+logits, hierarchical routing (block-level atomics) -------
__global__ __launch_bounds__(256) void k_gate(const float* __restrict__ x1,
                                              const float* __restrict__ g2,
                                              const float* __restrict__ gw,
                                              int* __restrict__ counts,
                                              int* __restrict__ ids,
                                              float* __restrict__ wts,
                                              float* __restrict__ load_sum) {
  __shared__ float lsum[NE];
  __shared__ int lcount[NE];
  __shared__ int lbase[NE];
  __shared__ int ltok[GATE_TPB * 2];
  __shared__ int lexp[GATE_TPB * 2];
  __shared__ float lwt[GATE_TPB * 2];
  int tid = threadIdx.x, wave = tid >> 6, lane = tid & 63;
  if (tid < NE) { lsum[tid] = 0.f; lcount[tid] = 0; }
  __syncthreads();
  int t0 = blockIdx.x * GATE_TPB;
#pragma unroll
  for (int tt = 0; tt < GATE_TPB / 4; tt++) {
    int tloc = tt * 4 + wave;
    int token = t0 + tloc;
    const float* xp = x1 + (size_t)token * D_DIM;
    float acc[NE] = {};
    float ss = 0.f;
    for (int d = lane; d < D_DIM; d += 64) {
      float xv = xp[d];
      ss += xv * xv;
      float hv = xv * g2[d];
#pragma unroll
      for (int e = 0; e < NE; e++) acc[e] += hv * gw[d * NE + e];
    }
#pragma unroll
    for (int off = 32; off; off >>= 1) ss += __shfl_xor(ss, off, 64);
#pragma unroll
    for (int e = 0; e < NE; e++)
#pragma unroll
      for (int off = 32; off; off >>= 1) acc[e] += __shfl_xor(acc[e], off, 64);
    if (lane == 0) {
      float sc = rsqrtf(ss * (1.0f / D_DIM) + 1e-6f);
      float mx = -1e30f;
#pragma unroll
      for (int e = 0; e < NE; e++) { acc[e] *= sc; mx = fmaxf(mx, acc[e]); }
      float p[NE], sum = 0.f;
#pragma unroll
      for (int e = 0; e < NE; e++) { p[e] = expf(acc[e] - mx); sum += p[e]; }
#pragma unroll
      for (int e = 0; e < NE; e++) p[e] /= sum;
      int i1 = 0;
#pragma unroll
      for (int e = 1; e < NE; e++) if (acc[e] > acc[i1]) i1 = e;
      int i2 = (i1 == 0) ? 1 : 0;
#pragma unroll
      for (int e = 0; e < NE; e++) if (e != i1 && acc[e] > acc[i2]) i2 = e;
      float denom = p[i1] + p[i2] + 1e-8f;
      int slot = tloc * 2;
      lexp[slot] = i1; ltok[slot] = token; lwt[slot] = p[i1] / denom;
      lexp[slot + 1] = i2; ltok[slot + 1] = token; lwt[slot + 1] = p[i2] / denom;
      atomicAdd(&lcount[i1], 1);
      atomicAdd(&lcount[i2], 1);
#pragma unroll
      for (int e = 0; e < NE; e++) atomicAdd(&lsum[e], p[e]);
    }
  }
  __syncthreads();
  if (tid < NE) {
    lbase[tid] = atomicAdd(&counts[tid], lcount[tid]);
    atomicAdd(&load_sum[tid], lsum[tid]);
    lcount[tid] = 0;
  }
  __syncthreads();
  if (tid < GATE_TPB * 2) {
    int e = lexp[tid];
    int off = atomicAdd(&lcount[e], 1);
    int pos = lbase[e] + off;
    ids[e * NTOK + pos] = ltok[tid];
    wts[e * NTOK + pos] = lwt[tid];
  }
}

__global__ void k_offsets(const int* __restrict__ counts, int* __restrict__ offsets) {
  if (threadIdx.x == 0 && blockIdx.x == 0) {
    int s = 0;
    for (int e = 0; e < NE; e++) { offsets[e] = s; s += counts[e]; }
  }
}

// ------- MoE gate/up bf16 MFMA GEMM, 2-phase double-buffered + SiLU*up*w -> act bf16 -------
// Block tile 128m x 64n; wave tile 64m x 32n of BOTH matrices (accg+accu = 64 regs).
// LDS per buffer: [As 4096][Bg 2048][Bu 2048] ushorts (16 KB), x2 = 32 KB.
__global__ __launch_bounds__(256) void k_moe_gateup(const ushort* __restrict__ h,
                                                    const ushort* __restrict__ wgT,
                                                    const ushort* __restrict__ wuT,
                                                    const int* __restrict__ ids,
                                                    const float* __restrict__ wts,
                                                    const int* __restrict__ counts,
                                                    const int* __restrict__ offsets,
                                                    ushort* __restrict__ act) {
  int e = blockIdx.z;
  int cnt = counts[e];
  int m0 = blockIdx.y * 128;
  if (m0 >= cnt) return;
  int n0 = blockIdx.x * 64;
  __shared__ __align__(16) ushort L0[8192], L1[8192];
  __shared__ int toks[128];
  __shared__ float wrow[128];
  int tid = threadIdx.x;
  if (tid < 128) {
    int mm = m0 + tid;
    toks[tid] = (mm < cnt) ? ids[e * NTOK + mm] : 0;
    wrow[tid] = (mm < cnt) ? wts[e * NTOK + mm] : 0.f;
  }
  __syncthreads();
  int wave = tid >> 6, lane = tid & 63, quad = lane >> 4, l15 = lane & 15;
  int wm = (wave >> 1) * 64, wn = (wave & 1) * 32;
  const ushort* Wg = wgT + (size_t)e * FF * D_DIM;
  const ushort* Wu = wuT + (size_t)e * FF * D_DIM;
  const ushort* src[4];
  int off[4];
  int srow = lane >> 2;
  int kc = ((lane & 3) ^ ((lane >> 3) & 3)) * 8;
#pragma unroll
  for (int j = 0; j < 4; j++) {
    int c = wave * 4 + j;
    if (c < 8) {
      src[j] = h + (size_t)toks[c * 16 + srow] * D_DIM + kc;
      off[j] = c * 512;
    } else if (c < 12) {
      src[j] = Wg + (size_t)(n0 + (c - 8) * 16 + srow) * D_DIM + kc;
      off[j] = 4096 + (c - 8) * 512;
    } else {
      src[j] = Wu + (size_t)(n0 + (c - 12) * 16 + srow) * D_DIM + kc;
      off[j] = 6144 + (c - 12) * 512;
    }
  }
  floatx4 accg[4][2], accu[4][2];
#pragma unroll
  for (int i = 0; i < 4; i++)
#pragma unroll
    for (int j = 0; j < 2; j++) {
      accg[i][j] = (floatx4){0.f, 0.f, 0.f, 0.f};
      accu[i][j] = (floatx4){0.f, 0.f, 0.f, 0.f};
    }
  auto stage = [&](ushort* Ld, int k0) {
#pragma unroll
    for (int j = 0; j < 4; j++) DMA16(src[j] + k0, Ld + off[j]);
  };
  auto compute = [&](const ushort* Ld) {
    const ushort* As = Ld;
    const ushort* Bg = Ld + 4096;
    const ushort* Bu = Ld + 6144;
    short8 aF[4], bgF[2], buF[2];
#pragma unroll
    for (int mt = 0; mt < 4; mt++) {
      int ar = wm + mt * 16 + l15;
      int sw = (quad ^ ((ar >> 1) & 3)) * 8;
      aF[mt] = *(short8*)&As[ar * 32 + sw];
    }
#pragma unroll
    for (int nt = 0; nt < 2; nt++) {
      int br = wn + nt * 16 + l15;
      int sw = (quad ^ ((br >> 1) & 3)) * 8;
      bgF[nt] = *(short8*)&Bg[br * 32 + sw];
      buF[nt] = *(short8*)&Bu[br * 32 + sw];
    }
#pragma unroll
    for (int mt = 0; mt < 4; mt++)
#pragma unroll
      for (int nt = 0; nt < 2; nt++) {
        accg[mt][nt] = mfma16(aF[mt], bgF[nt], accg[mt][nt]);
        accu[mt][nt] = mfma16(aF[mt], buF[nt], accu[mt][nt]);
      }
  };
  stage(L0, 0);
  __syncthreads();
  for (int t = 0; t < 32; t++) {
    if ((t & 1) == 0) {
      if (t + 1 < 32) stage(L1, (t + 1) << 5);
      compute(L0);
    } else {
      if (t + 1 < 32) stage(L0, (t + 1) << 5);
      compute(L1);
    }
    __syncthreads();
  }
  int aoff = offsets[e];
#pragma unroll
  for (int mt = 0; mt < 4; mt++) {
    int mrow = wm + mt * 16 + quad * 4;
#pragma unroll
    for (int nt = 0; nt < 2; nt++) {
      int col = n0 + wn + nt * 16 + l15;
#pragma unroll
      for (int r = 0; r < 4; r++) {
        int ml = mrow + r;
        if (m0 + ml < cnt) {
          float g = accg[mt][nt][r];
          float u = accu[mt][nt][r];
          float sil = g / (1.f + __expf(-g));
          act[(size_t)(aoff + m0 + ml) * FF + col] = f2bf(sil * u * wrow[ml]);
        }
      }
    }
  }
}

// ------- MoE down bf16 MFMA GEMM, 2-phase double-buffered, K-split x2, scatter-add -------
// LDS per buffer: [As 4096][Bs 4096] ushorts (16 KB), x2 = 32 KB.
__global__ __launch_bounds__(256) void k_moe_down(const ushort* __restrict__ act,
                                                  const ushort* __restrict__ wdT,
                                                  const int* __restrict__ ids,
                                                  const int* __restrict__ counts,
                                                  const int* __restrict__ offsets,
                                                  float* __restrict__ moe_acc) {
  int e = blockIdx.z & 7;
  int kh = blockIdx.z >> 3;
  int cnt = counts[e];
  int m0 = blockIdx.y * 128;
  if (m0 >= cnt) return;
  int n0 = blockIdx.x * 128;
  __shared__ __align__(16) ushort L0[8192], L1[8192];
  __shared__ int toks[128];
  int tid = threadIdx.x;
  if (tid < 128) {
    int mm = m0 + tid;
    toks[tid] = (mm < cnt) ? ids[e * NTOK + mm] : 0;
  }
  __syncthreads();
  int wave = tid >> 6, lane = tid & 63, quad = lane >> 4, l15 = lane & 15;
  int wm = (wave >> 1) * 64, wn = (wave & 1) * 64;
  int aoff = offsets[e];
  const ushort* Wd = wdT + (size_t)e * D_DIM * FF;
  const ushort* src[4];
  int off[4];
  int srow = lane >> 2;
  int kc = ((lane & 3) ^ ((lane >> 3) & 3)) * 8;
#pragma unroll
  for (int j = 0; j < 4; j++) {
    int c = wave * 4 + j;
    if (c < 8) {
      src[j] = act + (size_t)(aoff + m0 + c * 16 + srow) * FF + kc;
      off[j] = c * 512;
    } else {
      src[j] = Wd + (size_t)(n0 + (c - 8) * 16 + srow) * FF + kc;
      off[j] = 4096 + (c - 8) * 512;
    }
  }
  floatx4 acc[4][4];
#pragma unroll
  for (int i = 0; i < 4; i++)
#pragma unroll
    for (int j = 0; j < 4; j++) acc[i][j] = (floatx4){0.f, 0.f, 0.f, 0.f};
  auto stage = [&](ushort* Ld, int k0) {
#pragma unroll
    for (int j = 0; j < 4; j++) DMA16(src[j] + k0, Ld + off[j]);
  };
  auto compute = [&](const ushort* Ld) {
    const ushort* As = Ld;
    const ushort* Bs = Ld + 4096;
    short8 aF[4], bF[4];
#pragma unroll
    for (int mt = 0; mt < 4; mt++) {
      int ar = wm + mt * 16 + l15;
      int sw = (quad ^ ((ar >> 1) & 3)) * 8;
      aF[mt] = *(short8*)&As[ar * 32 + sw];
    }
#pragma unroll
    for (int nt = 0; nt < 4; nt++) {
      int br = wn + nt * 16 + l15;
      int sw = (quad ^ ((br >> 1) & 3)) * 8;
      bF[nt] = *(short8*)&Bs[br * 32 + sw];
    }
#pragma unroll
    for (int mt = 0; mt < 4; mt++)
#pragma unroll
      for (int nt = 0; nt < 4; nt++) acc[mt][nt] = mfma16(aF[mt], bF[nt], acc[mt][nt]);
  };
  int kbeg = kh * 1376;
  int nt = 43;  // 1376 / 32
  stage(L0, kbeg);
  __syncthreads();
  for (int t = 0; t < nt; t++) {
    if ((t & 1) == 0) {
      if (t + 1 < nt) stage(L1, kbeg + ((t + 1) << 5));
      compute(L0);
    } else {
      if (t + 1 < nt) stage(L0, kbeg + ((t + 1) << 5));
      compute(L1);
    }
    __syncthreads();
  }
#pragma unroll
  for (int mt = 0; mt < 4; mt++) {
    int mrow = wm + mt * 16 + quad * 4;
#pragma unroll
    for (int nt2 = 0; nt2 < 4; nt2++) {
      int col = n0 + wn + nt2 * 16 + l15;
#pragma unroll
      for (int r = 0; r < 4; r++) {
        int ml = mrow + r;
        if (m0 + ml < cnt)
          atomicAdd(&moe_acc[(size_t)toks[ml] * D_DIM + col], acc[mt][nt2][r]);
      }
    }
  }
}

__global__ __launch_bounds__(256) void k_add(const float* __restrict__ a,
                                             const float* __restrict__ b,
                                             float* __restrict__ o) {
  int i = blockIdx.x * 256 + threadIdx.x;
  float4 va = ((const float4*)a)[i];
  float4 vb = ((const float4*)b)[i];
  float4 vo;
  vo.x = va.x + vb.x; vo.y = va.y + vb.y; vo.z = va.z + vb.z; vo.w = va.w + vb.w;
  ((float4*)o)[i] = vo;
}

__global__ void k_aux(const int* __restrict__ counts, const float* __restrict__ load_sum,
                      float* __restrict__ out_aux) {
  if (threadIdx.x == 0 && blockIdx.x == 0) {
    float s = 0.f;
    for (int e = 0; e < NE; e++)
      s += ((float)counts[e] / (float)NSLOT) * (load_sum[e] / (float)NTOK);
    *out_aux = 0.01f * (float)NE * s;
  }
}

extern "C" void kernel_launch(void* const* d_in, const int* in_sizes, int n_in,
                              void* d_out, int out_size, void* d_ws, size_t ws_size,
                              hipStream_t stream) {
  const float* x = (const float*)d_in[0];
  const float* g1 = (const float*)d_in[1];
  const float* g2 = (const float*)d_in[2];
  const float* wq = (const float*)d_in[3];
  const float* wk = (const float*)d_in[4];
  const float* wv = (const float*)d_in[5];
  const float* wo = (const float*)d_in[6];
  const float* gate_w = (const float*)d_in[7];
  const float* we_gate = (const float*)d_in[8];
  const float* we_up = (const float*)d_in[9];
  const float* we_down = (const float*)d_in[10];
  float* out = (float*)d_out;

  char* w = (char*)d_ws;
  size_t o = 0;
  auto alloc = [&](size_t bytes) -> char* {
    char* p = w + o;
    o = (o + bytes + 255) & ~(size_t)255;
    return p;
  };
  ushort* h1h = (ushort*)alloc((size_t)NTOK * D_DIM * 2);
  ushort* h1l = (ushort*)alloc((size_t)NTOK * D_DIM * 2);
  float* qkvf = (float*)alloc((size_t)NTOK * 1536 * 4);
  ushort* qhi = (ushort*)alloc((size_t)HQn * T_LEN * 64 * 2);
  ushort* qlo = (ushort*)alloc((size_t)HQn * T_LEN * 64 * 2);
  ushort* khi = (ushort*)alloc((size_t)HKVn * T_LEN * 64 * 2);
  ushort* klo = (ushort*)alloc((size_t)HKVn * T_LEN * 64 * 2);
  ushort* vbth = (ushort*)alloc((size_t)HKVn * 64 * T_LEN * 2);
  ushort* vbtl = (ushort*)alloc((size_t)HKVn * 64 * T_LEN * 2);
  ushort* obh = (ushort*)alloc((size_t)NTOK * D_DIM * 2);
  ushort* obl = (ushort*)alloc((size_t)NTOK * D_DIM * 2);
  float* x1 = (float*)alloc((size_t)NTOK * D_DIM * 4);
  float* moe_acc = (float*)alloc((size_t)NTOK * D_DIM * 4);
  ushort* act = (ushort*)alloc((size_t)(NSLOT + 128) * FF * 2);
  ushort* qkvwTh = (ushort*)alloc((size_t)1536 * 1024 * 2);
  ushort* qkvwTl = (ushort*)alloc((size_t)1536 * 1024 * 2);
  ushort* woTh = (ushort*)alloc((size_t)1024 * 1024 * 2);
  ushort* woTl = (ushort*)alloc((size_t)1024 * 1024 * 2);
  ushort* h2h = (ushort*)alloc((size_t)NTOK * D_DIM * 2);
  ushort* h2l = (ushort*)alloc((size_t)NTOK * D_DIM * 2);
  ushort* wgT = (ushort*)alloc((size_t)NE * FF * D_DIM * 2);
  ushort* wuT = (ushort*)alloc((size_t)NE * FF * D_DIM * 2);
  ushort* wdT = (ushort*)alloc((size_t)NE * D_DIM * FF * 2);
  int* counts = (int*)alloc(NE * 4);
  int* offsets = (int*)alloc(NE * 4);
  float* load_sum = (float*)alloc(NE * 4);
  int* ids = (int*)alloc((size_t)NE * NTOK * 4);
  float* wts = (float*)alloc((size_t)NE * NTOK * 4);

  hipMemsetAsync(moe_acc, 0, (size_t)NTOK * D_DIM * 4, stream);
  hipMemsetAsync(counts, 0, 768, stream);  // counts+offsets+load_sum slots

  // weight transposes (hi/lo split for fp32-accurate attention path, bf16 for experts)
  k_cvtT2<<<dim3(32, 32), 256, 0, stream>>>(wq, qkvwTh, qkvwTl, 1024, 1024);
  k_cvtT2<<<dim3(8, 32), 256, 0, stream>>>(wk, qkvwTh + (size_t)1024 * 1024,
                                           qkvwTl + (size_t)1024 * 1024, 1024, 256);
  k_cvtT2<<<dim3(8, 32), 256, 0, stream>>>(wv, qkvwTh + (size_t)1280 * 1024,
                                           qkvwTl + (size_t)1280 * 1024, 1024, 256);
  k_cvtT2<<<dim3(32, 32), 256, 0, stream>>>(wo, woTh, woTl, 1024, 1024);
  k_cvtT<<<dim3(86, 32, 8), 256, 0, stream>>>(we_gate, wgT, 1024, 2752);
  k_cvtT<<<dim3(86, 32, 8), 256, 0, stream>>>(we_up, wuT, 1024, 2752);
  k_cvtT<<<dim3(32, 86, 8), 256, 0, stream>>>(we_down, wdT, 2752, 1024);

  // attention path (fp32-accurate via split-bf16 MFMA)
  k_rmsnorm2<<<NTOK, 256, 0, stream>>>(x, g1, h1h, h1l);
  k_sgemm<<<dim3(12, 32), 256, 0, stream>>>(h1h, h1l, qkvwTh, qkvwTl, qkvf, nullptr,
                                            1536, 1024);
  k_rope_cvt<<<T_LEN, 256, 0, stream>>>(qkvf, qhi, qlo, khi, klo);
  k_vT<<<dim3(64, 8), 256, 0, stream>>>(qkvf, vbth, vbtl);
  k_attn<<<dim3(16, 16), 256, 0, stream>>>(qhi, qlo, khi, klo, vbth, vbtl, obh, obl);
  k_sgemm<<<dim3(8, 32), 256, 0, stream>>>(obh, obl, woTh, woTl, x1, x, 1024, 1024);

  // moe
  k_rmsnorm2<<<NTOK, 256, 0, stream>>>(x1, g2, h2h, h2l);
  k_gate<<<NTOK / GATE_TPB, 256, 0, stream>>>(x1, g2, gate_w, counts, ids, wts, load_sum);
  k_offsets<<<1, 1, 0, stream>>>(counts, offsets);
  k_moe_gateup<<<dim3(43, 16, 8), 256, 0, stream>>>(h2h, wgT, wuT, ids, wts, counts,
                                                    offsets, act);
  k_moe_down<<<dim3(8, 16, 16), 256, 0, stream>>>(act, wdT, ids, counts, offsets, moe_acc);
  k_add<<<(NTOK * D_DIM) / (256 * 4), 256, 0, stream>>>(x1, moe_acc, out);
  k_aux<<<1, 1, 0, stream>>>(counts, load_sum, out + (size_t)NTOK * D_DIM);
}

// Round 6
// 683.309 us; speedup vs baseline: 1.0403x; 1.0403x over previous
//
#include <hip/hip_runtime.h>
#include <cstdint>

typedef __attribute__((ext_vector_type(8))) short short8;
typedef __attribute__((ext_vector_type(4))) float floatx4;
typedef __attribute__((ext_vector_type(4))) unsigned short ushort4v;
typedef unsigned short ushort;

#define T_LEN 2048
#define D_DIM 1024
#define HQn 16
#define HKVn 4
#define NE 8
#define FF 2752
#define NTOK 2048
#define NSLOT 4096
#define ATT_SCALE 0.125f
#define GATE_TPB 16

// counted vmcnt wait (N must be a literal)
#define WAITCNT(N) asm volatile("s_waitcnt vmcnt(" #N ")" ::: "memory")

__device__ inline ushort f2bf(float f) {
  union { float f; unsigned int i; } v; v.f = f;
  unsigned int r = v.i + 0x7fffu + ((v.i >> 16) & 1u);
  return (ushort)(r >> 16);
}
__device__ inline float bf2f(ushort h) {
  union { unsigned int i; float f; } v; v.i = ((unsigned int)h) << 16;
  return v.f;
}
__device__ inline void split8(const float* v, short8& hi, short8& lo) {
#pragma unroll
  for (int i = 0; i < 8; i++) {
    ushort h = f2bf(v[i]);
    hi[i] = (short)h;
    lo[i] = (short)f2bf(v[i] - bf2f(h));
  }
}
__device__ inline floatx4 mfma16(short8 a, short8 b, floatx4 c) {
  return __builtin_amdgcn_mfma_f32_16x16x32_bf16(a, b, c, 0, 0, 0);
}
// async global->LDS, 16B per lane; LDS dest = wave-uniform base + lane*16
#define DMA16(g, l)                                                              \
  __builtin_amdgcn_global_load_lds((const __attribute__((address_space(1))) void*)(g), \
                                   (__attribute__((address_space(3))) void*)(l), 16, 0, 0)

// ---------------- transpose+convert fp32 -> bf16 [C][R] (batch z) ----------------
__global__ __launch_bounds__(256) void k_cvtT(const float* __restrict__ src,
                                              ushort* __restrict__ dst, int R, int C) {
  __shared__ float tile[32][33];
  size_t sb = (size_t)blockIdx.z * R * C;
  const float* s = src + sb;
  ushort* d = dst + sb;
  int r0 = blockIdx.y * 32, c0 = blockIdx.x * 32;
  int tc = threadIdx.x & 31, tr = threadIdx.x >> 5;
#pragma unroll
  for (int i = 0; i < 4; i++)
    tile[tr + i * 8][tc] = s[(size_t)(r0 + tr + i * 8) * C + c0 + tc];
  __syncthreads();
#pragma unroll
  for (int i = 0; i < 4; i++) {
    int cc = tr + i * 8;
    d[(size_t)(c0 + cc) * R + r0 + tc] = f2bf(tile[tc][cc]);
  }
}

// ---------------- transpose+split fp32 -> hi/lo bf16 [C][R] ----------------
__global__ __launch_bounds__(256) void k_cvtT2(const float* __restrict__ src,
                                               ushort* __restrict__ dh,
                                               ushort* __restrict__ dl, int R, int C) {
  __shared__ float tile[32][33];
  int r0 = blockIdx.y * 32, c0 = blockIdx.x * 32;
  int tc = threadIdx.x & 31, tr = threadIdx.x >> 5;
#pragma unroll
  for (int i = 0; i < 4; i++)
    tile[tr + i * 8][tc] = src[(size_t)(r0 + tr + i * 8) * C + c0 + tc];
  __syncthreads();
#pragma unroll
  for (int i = 0; i < 4; i++) {
    int cc = tr + i * 8;
    float v = tile[tc][cc];
    ushort h = f2bf(v);
    dh[(size_t)(c0 + cc) * R + r0 + tc] = h;
    dl[(size_t)(c0 + cc) * R + r0 + tc] = f2bf(v - bf2f(h));
  }
}

// ---------------- RMSNorm fp32 -> hi/lo bf16 split ----------------
__global__ __launch_bounds__(256) void k_rmsnorm2(const float* __restrict__ x,
                                                  const float* __restrict__ g,
                                                  ushort* __restrict__ oh,
                                                  ushort* __restrict__ ol) {
  int row = blockIdx.x;
  int t = threadIdx.x;
  const float4* x4 = (const float4*)(x + (size_t)row * D_DIM);
  float4 v = x4[t];
  float ss = v.x * v.x + v.y * v.y + v.z * v.z + v.w * v.w;
#pragma unroll
  for (int off = 32; off; off >>= 1) ss += __shfl_xor(ss, off, 64);
  __shared__ float red[4];
  if ((t & 63) == 0) red[t >> 6] = ss;
  __syncthreads();
  float tot = red[0] + red[1] + red[2] + red[3];
  float sc = rsqrtf(tot * (1.0f / D_DIM) + 1e-6f);
  const float4* g4 = (const float4*)g;
  float4 gv = g4[t];
  float vals[4] = {v.x * gv.x * sc, v.y * gv.y * sc, v.z * gv.z * sc, v.w * gv.w * sc};
  ushort4v h4, l4;
#pragma unroll
  for (int i = 0; i < 4; i++) {
    ushort h = f2bf(vals[i]);
    h4[i] = h;
    l4[i] = f2bf(vals[i] - bf2f(h));
  }
  *(ushort4v*)(oh + (size_t)row * D_DIM + t * 4) = h4;
  *(ushort4v*)(ol + (size_t)row * D_DIM + t * 4) = l4;
}

// ------- split-bf16 emulated-fp32 MFMA GEMM, 3-buffer counted-vmcnt pipeline -------
// Block tile 64m x 128n, 4 waves, wave tile 32m x 64n (acc 32 regs).
// Tile t staged at iter t-2 (2 iterations of flight). Per iter:
//   vmcnt(SPW=6) [leave newest stage in flight] -> s_barrier -> stage(t+2) -> compute(t)
__global__ __launch_bounds__(256) void k_sgemm(const ushort* __restrict__ Ahg,
                                               const ushort* __restrict__ Alg,
                                               const ushort* __restrict__ Bhg,
                                               const ushort* __restrict__ Blg,
                                               float* __restrict__ C,
                                               const float* __restrict__ res,
                                               int N, int K) {
  __shared__ __align__(16) ushort L[36864];  // 3 x 12288 (24 KB each)
  int tid = threadIdx.x;
  int m0 = blockIdx.y * 64, n0 = blockIdx.x * 128;
  int wave = tid >> 6, lane = tid & 63, quad = lane >> 4, l15 = lane & 15;
  int wm = (wave >> 1) * 32, wn = (wave & 1) * 64;
  floatx4 acc[2][4];
#pragma unroll
  for (int i = 0; i < 2; i++)
#pragma unroll
    for (int j = 0; j < 4; j++) acc[i][j] = (floatx4){0.f, 0.f, 0.f, 0.f};
  const ushort* src[6];
  int off[6];
  int srow = lane >> 2;
  int kc = ((lane & 3) ^ ((lane >> 3) & 3)) * 8;
#pragma unroll
  for (int j = 0; j < 6; j++) {
    int c = wave * 6 + j;
    if (c < 4) {
      src[j] = Ahg + (size_t)(m0 + c * 16 + srow) * K + kc;
      off[j] = c * 512;
    } else if (c < 8) {
      src[j] = Alg + (size_t)(m0 + (c - 4) * 16 + srow) * K + kc;
      off[j] = 2048 + (c - 4) * 512;
    } else if (c < 16) {
      src[j] = Bhg + (size_t)(n0 + (c - 8) * 16 + srow) * K + kc;
      off[j] = 4096 + (c - 8) * 512;
    } else {
      src[j] = Blg + (size_t)(n0 + (c - 16) * 16 + srow) * K + kc;
      off[j] = 8192 + (c - 16) * 512;
    }
  }
  auto stage = [&](ushort* Ld, int k0) {
#pragma unroll
    for (int j = 0; j < 6; j++) DMA16(src[j] + k0, Ld + off[j]);
  };
  auto compute = [&](const ushort* Ld) {
    const ushort* Ah = Ld;
    const ushort* Al = Ld + 2048;
    const ushort* Bh = Ld + 4096;
    const ushort* Bl = Ld + 8192;
    short8 ah[2], al[2], bh[4], bl[4];
#pragma unroll
    for (int mt = 0; mt < 2; mt++) {
      int ar = wm + mt * 16 + l15;
      int sw = (quad ^ ((ar >> 1) & 3)) * 8;
      ah[mt] = *(short8*)&Ah[ar * 32 + sw];
      al[mt] = *(short8*)&Al[ar * 32 + sw];
    }
#pragma unroll
    for (int nt = 0; nt < 4; nt++) {
      int br = wn + nt * 16 + l15;
      int sw = (quad ^ ((br >> 1) & 3)) * 8;
      bh[nt] = *(short8*)&Bh[br * 32 + sw];
      bl[nt] = *(short8*)&Bl[br * 32 + sw];
    }
#pragma unroll
    for (int mt = 0; mt < 2; mt++)
#pragma unroll
      for (int nt = 0; nt < 4; nt++) {
        acc[mt][nt] = mfma16(ah[mt], bh[nt], acc[mt][nt]);
        acc[mt][nt] = mfma16(ah[mt], bl[nt], acc[mt][nt]);
        acc[mt][nt] = mfma16(al[mt], bh[nt], acc[mt][nt]);
      }
  };
  int ntile = K >> 5;
  stage(L, 0);
  stage(L + 12288, 32);
  int cb = 0;
  for (int t = 0; t < ntile; t++) {
    if (t + 1 < ntile) { WAITCNT(6); } else { WAITCNT(0); }
    __builtin_amdgcn_s_barrier();
    __builtin_amdgcn_sched_barrier(0);
    if (t + 2 < ntile) {
      int sb = cb + 2; if (sb >= 3) sb -= 3;
      stage(L + sb * 12288, (t + 2) << 5);
    }
    compute(L + cb * 12288);
    if (++cb == 3) cb = 0;
  }
#pragma unroll
  for (int mt = 0; mt < 2; mt++) {
    int row = m0 + wm + mt * 16 + quad * 4;
#pragma unroll
    for (int nt2 = 0; nt2 < 4; nt2++) {
      int col = n0 + wn + nt2 * 16 + l15;
#pragma unroll
      for (int r = 0; r < 4; r++) {
        float v = acc[mt][nt2][r];
        if (res) v += res[(size_t)(row + r) * N + col];
        C[(size_t)(row + r) * N + col] = v;
      }
    }
  }
}

// ------- RoPE fp32 -> split-bf16: qkvf [T,1536] -> qhi/qlo [HQ][T][64], khi/klo [HKV][T][64] -------
__global__ __launch_bounds__(256) void k_rope_cvt(const float* __restrict__ qkvf,
                                                  ushort* __restrict__ qhi,
                                                  ushort* __restrict__ qlo,
                                                  ushort* __restrict__ khi,
                                                  ushort* __restrict__ klo) {
  int t = blockIdx.x;
  const float* row = qkvf + (size_t)t * 1536;
  for (int it = threadIdx.x; it < (HQn + HKVn) * 32; it += 256) {
    int hh = it >> 5, i = it & 31;
    float inv = powf(10000.0f, -(float)i / 32.0f);
    float ang = (float)t * inv;
    float c = cosf(ang), s = sinf(ang);
    const float* p;
    ushort *dh, *dl;
    size_t base;
    if (hh < HQn) {
      p = row + hh * 64;
      base = ((size_t)hh * T_LEN + t) * 64;
      dh = qhi; dl = qlo;
    } else {
      int h2 = hh - HQn;
      p = row + 1024 + h2 * 64;
      base = ((size_t)h2 * T_LEN + t) * 64;
      dh = khi; dl = klo;
    }
    float a = p[i], b = p[i + 32];
    float v0 = a * c - b * s;
    float v1 = b * c + a * s;
    ushort h0 = f2bf(v0);
    dh[base + i] = h0;
    dl[base + i] = f2bf(v0 - bf2f(h0));
    ushort h1 = f2bf(v1);
    dh[base + i + 32] = h1;
    dl[base + i + 32] = f2bf(v1 - bf2f(h1));
  }
}

// ------- V transpose fp32 -> split-bf16: qkvf v-part -> vbth/vbtl [HKV*64][T] -------
__global__ __launch_bounds__(256) void k_vT(const float* __restrict__ qkvf,
                                            ushort* __restrict__ vbth,
                                            ushort* __restrict__ vbtl) {
  __shared__ float tile[32][33];
  int t0 = blockIdx.x * 32;
  int dh = blockIdx.y;
  int col0 = 1280 + dh * 32;
  int tc = threadIdx.x & 31, tr = threadIdx.x >> 5;
#pragma unroll
  for (int i = 0; i < 4; i++)
    tile[tr + i * 8][tc] = qkvf[(size_t)(t0 + tr + i * 8) * 1536 + col0 + tc];
  __syncthreads();
#pragma unroll
  for (int i = 0; i < 4; i++) {
    int dd = tr + i * 8;
    float v = tile[tc][dd];
    ushort h = f2bf(v);
    size_t idx = (size_t)(dh * 32 + dd) * T_LEN + t0 + tc;
    vbth[idx] = h;
    vbtl[idx] = f2bf(v - bf2f(h));
  }
}

// ------- split-bf16 MFMA flash attention, DMA-staged K/V, balanced q-tile pairing -------
__global__ __launch_bounds__(256) void k_attn(const ushort* __restrict__ qhi,
                                              const ushort* __restrict__ qlo,
                                              const ushort* __restrict__ khi,
                                              const ushort* __restrict__ klo,
                                              const ushort* __restrict__ vbth,
                                              const ushort* __restrict__ vbtl,
                                              ushort* __restrict__ obh,
                                              ushort* __restrict__ obl) {
  __shared__ __align__(16) ushort Kh[4096], Kl[4096], Vh[4096], Vl[4096];
  __shared__ ushort Psh[4 * 16 * 72], Psl[4 * 16 * 72];
  int qh = blockIdx.y, kvh = qh >> 2;
  int tid = threadIdx.x, wave = tid >> 6, lane = tid & 63;
  int quad = lane >> 4, l15 = lane & 15;
  int sx = l15 >> 1;  // read-side swizzle (row>>1)&7 for rows nt*16+l15
  int rlb = lane >> 3;                      // staging: row-in-8
  int csb = (lane & 7) ^ (lane >> 4);       // staging: source chunk base
#pragma unroll 1
  for (int hf = 0; hf < 2; hf++) {
    int xt = hf ? (31 - (int)blockIdx.x) : (int)blockIdx.x;
    int r0 = xt * 64;
    const ushort* qbh_ = qhi + ((size_t)qh * T_LEN + r0 + wave * 16 + l15) * 64;
    const ushort* qbl_ = qlo + ((size_t)qh * T_LEN + r0 + wave * 16 + l15) * 64;
    short8 aqh0 = *(const short8*)&qbh_[quad * 8];
    short8 aqh1 = *(const short8*)&qbh_[32 + quad * 8];
    short8 aql0 = *(const short8*)&qbl_[quad * 8];
    short8 aql1 = *(const short8*)&qbl_[32 + quad * 8];
    floatx4 oacc[4];
#pragma unroll
    for (int nt = 0; nt < 4; nt++) oacc[nt] = (floatx4){0.f, 0.f, 0.f, 0.f};
    float mrun[4], lrun[4];
#pragma unroll
    for (int r = 0; r < 4; r++) { mrun[r] = -INFINITY; lrun[r] = 0.f; }
    for (int cc = 0; cc <= xt; cc++) {
      __syncthreads();  // all waves done reading previous tile
      if (wave < 2) {
        const ushort* G = (wave == 0) ? khi : klo;
        ushort* L = (wave == 0) ? Kh : Kl;
        size_t rbase = (size_t)kvh * T_LEN + cc * 64;
#pragma unroll
        for (int i = 0; i < 8; i++) {
          int ch = csb ^ ((i & 1) * 4);
          DMA16(G + (rbase + i * 8 + rlb) * 64 + ch * 8, L + i * 512);
        }
      } else {
        const ushort* G = (wave == 2) ? vbth : vbtl;
        ushort* L = (wave == 2) ? Vh : Vl;
#pragma unroll
        for (int i = 0; i < 8; i++) {
          int ch = csb ^ ((i & 1) * 4);
          DMA16(G + ((size_t)(kvh * 64 + i * 8 + rlb)) * T_LEN + cc * 64 + ch * 8,
                L + i * 512);
        }
      }
      __syncthreads();  // DMA landed (vmcnt drained by barrier)
      floatx4 s[4];
#pragma unroll
      for (int nt = 0; nt < 4; nt++) {
        int row = nt * 16 + l15;
        short8 bh0 = *(short8*)&Kh[row * 64 + (quad ^ sx) * 8];
        short8 bh1 = *(short8*)&Kh[row * 64 + ((4 + quad) ^ sx) * 8];
        short8 bl0 = *(short8*)&Kl[row * 64 + (quad ^ sx) * 8];
        short8 bl1 = *(short8*)&Kl[row * 64 + ((4 + quad) ^ sx) * 8];
        floatx4 z = (floatx4){0.f, 0.f, 0.f, 0.f};
        z = mfma16(aqh0, bh0, z);
        z = mfma16(aqh1, bh1, z);
        z = mfma16(aqh0, bl0, z);
        z = mfma16(aqh1, bl1, z);
        z = mfma16(aql0, bh0, z);
        z = mfma16(aql1, bh1, z);
        s[nt] = z;
      }
      int rowg0 = r0 + wave * 16 + quad * 4;
#pragma unroll
      for (int nt = 0; nt < 4; nt++) {
        int colg = cc * 64 + nt * 16 + l15;
#pragma unroll
        for (int r = 0; r < 4; r++) {
          float v = s[nt][r] * ATT_SCALE;
          s[nt][r] = (colg > rowg0 + r) ? -INFINITY : v;
        }
      }
      float mnew[4], alpha[4], psum[4];
#pragma unroll
      for (int r = 0; r < 4; r++) {
        float mx = fmaxf(fmaxf(s[0][r], s[1][r]), fmaxf(s[2][r], s[3][r]));
#pragma unroll
        for (int off = 1; off < 16; off <<= 1) mx = fmaxf(mx, __shfl_xor(mx, off, 64));
        mnew[r] = fmaxf(mrun[r], mx);
        psum[r] = 0.f;
      }
#pragma unroll
      for (int nt = 0; nt < 4; nt++)
#pragma unroll
        for (int r = 0; r < 4; r++) {
          float p = __expf(s[nt][r] - mnew[r]);
          s[nt][r] = p;
          psum[r] += p;
        }
#pragma unroll
      for (int r = 0; r < 4; r++) {
        float ps = psum[r];
#pragma unroll
        for (int off = 1; off < 16; off <<= 1) ps += __shfl_xor(ps, off, 64);
        alpha[r] = __expf(mrun[r] - mnew[r]);
        lrun[r] = lrun[r] * alpha[r] + ps;
        mrun[r] = mnew[r];
      }
#pragma unroll
      for (int nt = 0; nt < 4; nt++)
#pragma unroll
        for (int r = 0; r < 4; r++) oacc[nt][r] *= alpha[r];
#pragma unroll
      for (int nt = 0; nt < 4; nt++)
#pragma unroll
        for (int r = 0; r < 4; r++) {
          float p = s[nt][r];
          ushort ph = f2bf(p);
          Psh[wave * 1152 + (quad * 4 + r) * 72 + nt * 16 + l15] = ph;
          Psl[wave * 1152 + (quad * 4 + r) * 72 + nt * 16 + l15] = f2bf(p - bf2f(ph));
        }
      short8 aph0 = *(short8*)&Psh[wave * 1152 + l15 * 72 + quad * 8];
      short8 aph1 = *(short8*)&Psh[wave * 1152 + l15 * 72 + 32 + quad * 8];
      short8 apl0 = *(short8*)&Psl[wave * 1152 + l15 * 72 + quad * 8];
      short8 apl1 = *(short8*)&Psl[wave * 1152 + l15 * 72 + 32 + quad * 8];
#pragma unroll
      for (int nt = 0; nt < 4; nt++) {
        int row = nt * 16 + l15;
        short8 bvh0 = *(short8*)&Vh[row * 64 + (quad ^ sx) * 8];
        short8 bvh1 = *(short8*)&Vh[row * 64 + ((4 + quad) ^ sx) * 8];
        short8 bvl0 = *(short8*)&Vl[row * 64 + (quad ^ sx) * 8];
        short8 bvl1 = *(short8*)&Vl[row * 64 + ((4 + quad) ^ sx) * 8];
        oacc[nt] = mfma16(aph0, bvh0, oacc[nt]);
        oacc[nt] = mfma16(aph1, bvh1, oacc[nt]);
        oacc[nt] = mfma16(aph0, bvl0, oacc[nt]);
        oacc[nt] = mfma16(aph1, bvl1, oacc[nt]);
        oacc[nt] = mfma16(apl0, bvh0, oacc[nt]);
        oacc[nt] = mfma16(apl1, bvh1, oacc[nt]);
      }
    }
#pragma unroll
    for (int nt = 0; nt < 4; nt++)
#pragma unroll
      for (int r = 0; r < 4; r++) {
        int rowg = r0 + wave * 16 + quad * 4 + r;
        float v = oacc[nt][r] / lrun[r];
        ushort h = f2bf(v);
        size_t idx = (size_t)rowg * D_DIM + qh * 64 + nt * 16 + l15;
        obh[idx] = h;
        obl[idx] = f2bf(v - bf2f(h));
      }
  }
}

// ------- gate: fp32 rmsnorm+logits, hierarchical routing (block-level atomics) -------
__global__ __launch_bounds__(256) void k_gate(const float* __restrict__ x1,
                                              const float* __restrict__ g2,
                                              const float* __restrict__ gw,
                                              int* __restrict__ counts,
                                              int* __restrict__ ids,
                                              float* __restrict__ wts,
                                              float* __restrict__ load_sum) {
  __shared__ float lsum[NE];
  __shared__ int lcount[NE];
  __shared__ int lbase[NE];
  __shared__ int ltok[GATE_TPB * 2];
  __shared__ int lexp[GATE_TPB * 2];
  __shared__ float lwt[GATE_TPB * 2];
  int tid = threadIdx.x, wave = tid >> 6, lane = tid & 63;
  if (tid < NE) { lsum[tid] = 0.f; lcount[tid] = 0; }
  __syncthreads();
  int t0 = blockIdx.x * GATE_TPB;
#pragma unroll
  for (int tt = 0; tt < GATE_TPB / 4; tt++) {
    int tloc = tt * 4 + wave;
    int token = t0 + tloc;
    const float* xp = x1 + (size_t)token * D_DIM;
    float acc[NE] = {};
    float ss = 0.f;
    for (int d = lane; d < D_DIM; d += 64) {
      float xv = xp[d];
      ss += xv * xv;
      float hv = xv * g2[d];
#pragma unroll
      for (int e = 0; e < NE; e++) acc[e] += hv * gw[d * NE + e];
    }
#pragma unroll
    for (int off = 32; off; off >>= 1) ss += __shfl_xor(ss, off, 64);
#pragma unroll
    for (int e = 0; e < NE; e++)
#pragma unroll
      for (int off = 32; off; off >>= 1) acc[e] += __shfl_xor(acc[e], off, 64);
    if (lane == 0) {
      float sc = rsqrtf(ss * (1.0f / D_DIM) + 1e-6f);
      float mx = -1e30f;
#pragma unroll
      for (int e = 0; e < NE; e++) { acc[e] *= sc; mx = fmaxf(mx, acc[e]); }
      float p[NE], sum = 0.f;
#pragma unroll
      for (int e = 0; e < NE; e++) { p[e] = expf(acc[e] - mx); sum += p[e]; }
#pragma unroll
      for (int e = 0; e < NE; e++) p[e] /= sum;
      int i1 = 0;
#pragma unroll
      for (int e = 1; e < NE; e++) if (acc[e] > acc[i1]) i1 = e;
      int i2 = (i1 == 0) ? 1 : 0;
#pragma unroll
      for (int e = 0; e < NE; e++) if (e != i1 && acc[e] > acc[i2]) i2 = e;
      float denom = p[i1] + p[i2] + 1e-8f;
      int slot = tloc * 2;
      lexp[slot] = i1; ltok[slot] = token; lwt[slot] = p[i1] / denom;
      lexp[slot + 1] = i2; ltok[slot + 1] = token; lwt[slot + 1] = p[i2] / denom;
      atomicAdd(&lcount[i1], 1);
      atomicAdd(&lcount[i2], 1);
#pragma unroll
      for (int e = 0; e < NE; e++) atomicAdd(&lsum[e], p[e]);
    }
  }
  __syncthreads();
  if (tid < NE) {
    lbase[tid] = atomicAdd(&counts[tid], lcount[tid]);
    atomicAdd(&load_sum[tid], lsum[tid]);
    lcount[tid] = 0;
  }
  __syncthreads();
  if (tid < GATE_TPB * 2) {
    int e = lexp[tid];
    int off = atomicAdd(&lcount[e], 1);
    int pos = lbase[e] + off;
    ids[e * NTOK + pos] = ltok[tid];
    wts[e * NTOK + pos] = lwt[tid];
  }
}

__global__ void k_offsets(const int* __restrict__ counts, int* __restrict__ offsets) {
  if (threadIdx.x == 0 && blockIdx.x == 0) {
    int s = 0;
    for (int e = 0; e < NE; e++) { offsets[e] = s; s += counts[e]; }
  }
}

// ------- MoE gate/up bf16 MFMA GEMM, 3-buffer counted-vmcnt pipeline + SiLU -------
// Block tile 128m x 64n; wave tile 64m x 32n of BOTH matrices (accg+accu = 64 regs).
// LDS: 3 x 16 KB = 48 KB. SPW = 4 loads/wave/stage.
__global__ __launch_bounds__(256) void k_moe_gateup(const ushort* __restrict__ h,
                                                    const ushort* __restrict__ wgT,
                                                    const ushort* __restrict__ wuT,
                                                    const int* __restrict__ ids,
                                                    const float* __restrict__ wts,
                                                    const int* __restrict__ counts,
                                                    const int* __restrict__ offsets,
                                                    ushort* __restrict__ act) {
  int e = blockIdx.z;
  int cnt = counts[e];
  int m0 = blockIdx.y * 128;
  if (m0 >= cnt) return;
  int n0 = blockIdx.x * 64;
  __shared__ __align__(16) ushort L[24576];  // 3 x 8192
  __shared__ int toks[128];
  __shared__ float wrow[128];
  int tid = threadIdx.x;
  if (tid < 128) {
    int mm = m0 + tid;
    toks[tid] = (mm < cnt) ? ids[e * NTOK + mm] : 0;
    wrow[tid] = (mm < cnt) ? wts[e * NTOK + mm] : 0.f;
  }
  __syncthreads();
  int wave = tid >> 6, lane = tid & 63, quad = lane >> 4, l15 = lane & 15;
  int wm = (wave >> 1) * 64, wn = (wave & 1) * 32;
  const ushort* Wg = wgT + (size_t)e * FF * D_DIM;
  const ushort* Wu = wuT + (size_t)e * FF * D_DIM;
  const ushort* src[4];
  int off[4];
  int srow = lane >> 2;
  int kc = ((lane & 3) ^ ((lane >> 3) & 3)) * 8;
#pragma unroll
  for (int j = 0; j < 4; j++) {
    int c = wave * 4 + j;
    if (c < 8) {
      src[j] = h + (size_t)toks[c * 16 + srow] * D_DIM + kc;
      off[j] = c * 512;
    } else if (c < 12) {
      src[j] = Wg + (size_t)(n0 + (c - 8) * 16 + srow) * D_DIM + kc;
      off[j] = 4096 + (c - 8) * 512;
    } else {
      src[j] = Wu + (size_t)(n0 + (c - 12) * 16 + srow) * D_DIM + kc;
      off[j] = 6144 + (c - 12) * 512;
    }
  }
  floatx4 accg[4][2], accu[4][2];
#pragma unroll
  for (int i = 0; i < 4; i++)
#pragma unroll
    for (int j = 0; j < 2; j++) {
      accg[i][j] = (floatx4){0.f, 0.f, 0.f, 0.f};
      accu[i][j] = (floatx4){0.f, 0.f, 0.f, 0.f};
    }
  auto stage = [&](ushort* Ld, int k0) {
#pragma unroll
    for (int j = 0; j < 4; j++) DMA16(src[j] + k0, Ld + off[j]);
  };
  auto compute = [&](const ushort* Ld) {
    const ushort* As = Ld;
    const ushort* Bg = Ld + 4096;
    const ushort* Bu = Ld + 6144;
    short8 aF[4], bgF[2], buF[2];
#pragma unroll
    for (int mt = 0; mt < 4; mt++) {
      int ar = wm + mt * 16 + l15;
      int sw = (quad ^ ((ar >> 1) & 3)) * 8;
      aF[mt] = *(short8*)&As[ar * 32 + sw];
    }
#pragma unroll
    for (int nt = 0; nt < 2; nt++) {
      int br = wn + nt * 16 + l15;
      int sw = (quad ^ ((br >> 1) & 3)) * 8;
      bgF[nt] = *(short8*)&Bg[br * 32 + sw];
      buF[nt] = *(short8*)&Bu[br * 32 + sw];
    }
#pragma unroll
    for (int mt = 0; mt < 4; mt++)
#pragma unroll
      for (int nt = 0; nt < 2; nt++) {
        accg[mt][nt] = mfma16(aF[mt], bgF[nt], accg[mt][nt]);
        accu[mt][nt] = mfma16(aF[mt], buF[nt], accu[mt][nt]);
      }
  };
  stage(L, 0);
  stage(L + 8192, 32);
  int cb = 0;
  for (int t = 0; t < 32; t++) {
    if (t + 1 < 32) { WAITCNT(4); } else { WAITCNT(0); }
    __builtin_amdgcn_s_barrier();
    __builtin_amdgcn_sched_barrier(0);
    if (t + 2 < 32) {
      int sb = cb + 2; if (sb >= 3) sb -= 3;
      stage(L + sb * 8192, (t + 2) << 5);
    }
    compute(L + cb * 8192);
    if (++cb == 3) cb = 0;
  }
  int aoff = offsets[e];
#pragma unroll
  for (int mt = 0; mt < 4; mt++) {
    int mrow = wm + mt * 16 + quad * 4;
#pragma unroll
    for (int nt = 0; nt < 2; nt++) {
      int col = n0 + wn + nt * 16 + l15;
#pragma unroll
      for (int r = 0; r < 4; r++) {
        int ml = mrow + r;
        if (m0 + ml < cnt) {
          float g = accg[mt][nt][r];
          float u = accu[mt][nt][r];
          float sil = g / (1.f + __expf(-g));
          act[(size_t)(aoff + m0 + ml) * FF + col] = f2bf(sil * u * wrow[ml]);
        }
      }
    }
  }
}

// ------- MoE down bf16 MFMA GEMM, 3-buffer counted-vmcnt pipeline, K-split x2 -------
// LDS: 3 x 16 KB = 48 KB. SPW = 4 loads/wave/stage.
__global__ __launch_bounds__(256) void k_moe_down(const ushort* __restrict__ act,
                                                  const ushort* __restrict__ wdT,
                                                  const int* __restrict__ ids,
                                                  const int* __restrict__ counts,
                                                  const int* __restrict__ offsets,
                                                  float* __restrict__ moe_acc) {
  int e = blockIdx.z & 7;
  int kh = blockIdx.z >> 3;
  int cnt = counts[e];
  int m0 = blockIdx.y * 128;
  if (m0 >= cnt) return;
  int n0 = blockIdx.x * 128;
  __shared__ __align__(16) ushort L[24576];  // 3 x 8192
  __shared__ int toks[128];
  int tid = threadIdx.x;
  if (tid < 128) {
    int mm = m0 + tid;
    toks[tid] = (mm < cnt) ? ids[e * NTOK + mm] : 0;
  }
  __syncthreads();
  int wave = tid >> 6, lane = tid & 63, quad = lane >> 4, l15 = lane & 15;
  int wm = (wave >> 1) * 64, wn = (wave & 1) * 64;
  int aoff = offsets[e];
  const ushort* Wd = wdT + (size_t)e * D_DIM * FF;
  const ushort* src[4];
  int off[4];
  int srow = lane >> 2;
  int kc = ((lane & 3) ^ ((lane >> 3) & 3)) * 8;
#pragma unroll
  for (int j = 0; j < 4; j++) {
    int c = wave * 4 + j;
    if (c < 8) {
      src[j] = act + (size_t)(aoff + m0 + c * 16 + srow) * FF + kc;
      off[j] = c * 512;
    } else {
      src[j] = Wd + (size_t)(n0 + (c - 8) * 16 + srow) * FF + kc;
      off[j] = 4096 + (c - 8) * 512;
    }
  }
  floatx4 acc[4][4];
#pragma unroll
  for (int i = 0; i < 4; i++)
#pragma unroll
    for (int j = 0; j < 4; j++) acc[i][j] = (floatx4){0.f, 0.f, 0.f, 0.f};
  auto stage = [&](ushort* Ld, int k0) {
#pragma unroll
    for (int j = 0; j < 4; j++) DMA16(src[j] + k0, Ld + off[j]);
  };
  auto compute = [&](const ushort* Ld) {
    const ushort* As = Ld;
    const ushort* Bs = Ld + 4096;
    short8 aF[4], bF[4];
#pragma unroll
    for (int mt = 0; mt < 4; mt++) {
      int ar = wm + mt * 16 + l15;
      int sw = (quad ^ ((ar >> 1) & 3)) * 8;
      aF[mt] = *(short8*)&As[ar * 32 + sw];
    }
#pragma unroll
    for (int nt = 0; nt < 4; nt++) {
      int br = wn + nt * 16 + l15;
      int sw = (quad ^ ((br >> 1) & 3)) * 8;
      bF[nt] = *(short8*)&Bs[br * 32 + sw];
    }
#pragma unroll
    for (int mt = 0; mt < 4; mt++)
#pragma unroll
      for (int nt = 0; nt < 4; nt++) acc[mt][nt] = mfma16(aF[mt], bF[nt], acc[mt][nt]);
  };
  int kbeg = kh * 1376;
  stage(L, kbeg);
  stage(L + 8192, kbeg + 32);
  int cb = 0;
  for (int t = 0; t < 43; t++) {
    if (t + 1 < 43) { WAITCNT(4); } else { WAITCNT(0); }
    __builtin_amdgcn_s_barrier();
    __builtin_amdgcn_sched_barrier(0);
    if (t + 2 < 43) {
      int sb = cb + 2; if (sb >= 3) sb -= 3;
      stage(L + sb * 8192, kbeg + ((t + 2) << 5));
    }
    compute(L + cb * 8192);
    if (++cb == 3) cb = 0;
  }
#pragma unroll
  for (int mt = 0; mt < 4; mt++) {
    int mrow = wm + mt * 16 + quad * 4;
#pragma unroll
    for (int nt2 = 0; nt2 < 4; nt2++) {
      int col = n0 + wn + nt2 * 16 + l15;
#pragma unroll
      for (int r = 0; r < 4; r++) {
        int ml = mrow + r;
        if (m0 + ml < cnt)
          atomicAdd(&moe_acc[(size_t)toks[ml] * D_DIM + col], acc[mt][nt2][r]);
      }
    }
  }
}

__global__ __launch_bounds__(256) void k_add(const float* __restrict__ a,
                                             const float* __restrict__ b,
                                             float* __restrict__ o) {
  int i = blockIdx.x * 256 + threadIdx.x;
  float4 va = ((const float4*)a)[i];
  float4 vb = ((const float4*)b)[i];
  float4 vo;
  vo.x = va.x + vb.x; vo.y = va.y + vb.y; vo.z = va.z + vb.z; vo.w = va.w + vb.w;
  ((float4*)o)[i] = vo;
}

__global__ void k_aux(const int* __restrict__ counts, const float* __restrict__ load_sum,
                      float* __restrict__ out_aux) {
  if (threadIdx.x == 0 && blockIdx.x == 0) {
    float s = 0.f;
    for (int e = 0; e < NE; e++)
      s += ((float)counts[e] / (float)NSLOT) * (load_sum[e] / (float)NTOK);
    *out_aux = 0.01f * (float)NE * s;
  }
}

extern "C" void kernel_launch(void* const* d_in, const int* in_sizes, int n_in,
                              void* d_out, int out_size, void* d_ws, size_t ws_size,
                              hipStream_t stream) {
  const float* x = (const float*)d_in[0];
  const float* g1 = (const float*)d_in[1];
  const float* g2 = (const float*)d_in[2];
  const float* wq = (const float*)d_in[3];
  const float* wk = (const float*)d_in[4];
  const float* wv = (const float*)d_in[5];
  const float* wo = (const float*)d_in[6];
  const float* gate_w = (const float*)d_in[7];
  const float* we_gate = (const float*)d_in[8];
  const float* we_up = (const float*)d_in[9];
  const float* we_down = (const float*)d_in[10];
  float* out = (float*)d_out;

  char* w = (char*)d_ws;
  size_t o = 0;
  auto alloc = [&](size_t bytes) -> char* {
    char* p = w + o;
    o = (o + bytes + 255) & ~(size_t)255;
    return p;
  };
  ushort* h1h = (ushort*)alloc((size_t)NTOK * D_DIM * 2);
  ushort* h1l = (ushort*)alloc((size_t)NTOK * D_DIM * 2);
  float* qkvf = (float*)alloc((size_t)NTOK * 1536 * 4);
  ushort* qhi = (ushort*)alloc((size_t)HQn * T_LEN * 64 * 2);
  ushort* qlo = (ushort*)alloc((size_t)HQn * T_LEN * 64 * 2);
  ushort* khi = (ushort*)alloc((size_t)HKVn * T_LEN * 64 * 2);
  ushort* klo = (ushort*)alloc((size_t)HKVn * T_LEN * 64 * 2);
  ushort* vbth = (ushort*)alloc((size_t)HKVn * 64 * T_LEN * 2);
  ushort* vbtl = (ushort*)alloc((size_t)HKVn * 64 * T_LEN * 2);
  ushort* obh = (ushort*)alloc((size_t)NTOK * D_DIM * 2);
  ushort* obl = (ushort*)alloc((size_t)NTOK * D_DIM * 2);
  float* x1 = (float*)alloc((size_t)NTOK * D_DIM * 4);
  float* moe_acc = (float*)alloc((size_t)NTOK * D_DIM * 4);
  ushort* act = (ushort*)alloc((size_t)(NSLOT + 128) * FF * 2);
  ushort* qkvwTh = (ushort*)alloc((size_t)1536 * 1024 * 2);
  ushort* qkvwTl = (ushort*)alloc((size_t)1536 * 1024 * 2);
  ushort* woTh = (ushort*)alloc((size_t)1024 * 1024 * 2);
  ushort* woTl = (ushort*)alloc((size_t)1024 * 1024 * 2);
  ushort* h2h = (ushort*)alloc((size_t)NTOK * D_DIM * 2);
  ushort* h2l = (ushort*)alloc((size_t)NTOK * D_DIM * 2);
  ushort* wgT = (ushort*)alloc((size_t)NE * FF * D_DIM * 2);
  ushort* wuT = (ushort*)alloc((size_t)NE * FF * D_DIM * 2);
  ushort* wdT = (ushort*)alloc((size_t)NE * D_DIM * FF * 2);
  int* counts = (int*)alloc(NE * 4);
  int* offsets = (int*)alloc(NE * 4);
  float* load_sum = (float*)alloc(NE * 4);
  int* ids = (int*)alloc((size_t)NE * NTOK * 4);
  float* wts = (float*)alloc((size_t)NE * NTOK * 4);

  hipMemsetAsync(moe_acc, 0, (size_t)NTOK * D_DIM * 4, stream);
  hipMemsetAsync(counts, 0, 768, stream);  // counts+offsets+load_sum slots

  // weight transposes (hi/lo split for fp32-accurate attention path, bf16 for experts)
  k_cvtT2<<<dim3(32, 32), 256, 0, stream>>>(wq, qkvwTh, qkvwTl, 1024, 1024);
  k_cvtT2<<<dim3(8, 32), 256, 0, stream>>>(wk, qkvwTh + (size_t)1024 * 1024,
                                           qkvwTl + (size_t)1024 * 1024, 1024, 256);
  k_cvtT2<<<dim3(8, 32), 256, 0, stream>>>(wv, qkvwTh + (size_t)1280 * 1024,
                                           qkvwTl + (size_t)1280 * 1024, 1024, 256);
  k_cvtT2<<<dim3(32, 32), 256, 0, stream>>>(wo, woTh, woTl, 1024, 1024);
  k_cvtT<<<dim3(86, 32, 8), 256, 0, stream>>>(we_gate, wgT, 1024, 2752);
  k_cvtT<<<dim3(86, 32, 8), 256, 0, stream>>>(we_up, wuT, 1024, 2752);
  k_cvtT<<<dim3(32, 86, 8), 256, 0, stream>>>(we_down, wdT, 2752, 1024);

  // attention path (fp32-accurate via split-bf16 MFMA)
  k_rmsnorm2<<<NTOK, 256, 0, stream>>>(x, g1, h1h, h1l);
  k_sgemm<<<dim3(12, 32), 256, 0, stream>>>(h1h, h1l, qkvwTh, qkvwTl, qkvf, nullptr,
                                            1536, 1024);
  k_rope_cvt<<<T_LEN, 256, 0, stream>>>(qkvf, qhi, qlo, khi, klo);
  k_vT<<<dim3(64, 8), 256, 0, stream>>>(qkvf, vbth, vbtl);
  k_attn<<<dim3(16, 16), 256, 0, stream>>>(qhi, qlo, khi, klo, vbth, vbtl, obh, obl);
  k_sgemm<<<dim3(8, 32), 256, 0, stream>>>(obh, obl, woTh, woTl, x1, x, 1024, 1024);

  // moe
  k_rmsnorm2<<<NTOK, 256, 0, stream>>>(x1, g2, h2h, h2l);
  k_gate<<<NTOK / GATE_TPB, 256, 0, stream>>>(x1, g2, gate_w, counts, ids, wts, load_sum);
  k_offsets<<<1, 1, 0, stream>>>(counts, offsets);
  k_moe_gateup<<<dim3(43, 16, 8), 256, 0, stream>>>(h2h, wgT, wuT, ids, wts, counts,
                                                    offsets, act);
  k_moe_down<<<dim3(8, 16, 16), 256, 0, stream>>>(act, wdT, ids, counts, offsets, moe_acc);
  k_add<<<(NTOK * D_DIM) / (256 * 4), 256, 0, stream>>>(x1, moe_acc, out);
  k_aux<<<1, 1, 0, stream>>>(counts, load_sum, out + (size_t)NTOK * D_DIM);
}

// Round 7
// 675.745 us; speedup vs baseline: 1.0520x; 1.0112x over previous
//
#include <hip/hip_runtime.h>
#include <cstdint>

typedef __attribute__((ext_vector_type(8))) short short8;
typedef __attribute__((ext_vector_type(4))) float floatx4;
typedef __attribute__((ext_vector_type(4))) unsigned short ushort4v;
typedef unsigned short ushort;

#define T_LEN 2048
#define D_DIM 1024
#define HQn 16
#define HKVn 4
#define NE 8
#define FF 2752
#define NTOK 2048
#define NSLOT 4096
#define ATT_SCALE 0.125f
#define GATE_TPB 16

// counted vmcnt wait (N must be a literal)
#define WAITCNT(N) asm volatile("s_waitcnt vmcnt(" #N ")" ::: "memory")

__device__ inline ushort f2bf(float f) {
  union { float f; unsigned int i; } v; v.f = f;
  unsigned int r = v.i + 0x7fffu + ((v.i >> 16) & 1u);
  return (ushort)(r >> 16);
}
__device__ inline float bf2f(ushort h) {
  union { unsigned int i; float f; } v; v.i = ((unsigned int)h) << 16;
  return v.f;
}
__device__ inline void split8(const float* v, short8& hi, short8& lo) {
#pragma unroll
  for (int i = 0; i < 8; i++) {
    ushort h = f2bf(v[i]);
    hi[i] = (short)h;
    lo[i] = (short)f2bf(v[i] - bf2f(h));
  }
}
__device__ inline floatx4 mfma16(short8 a, short8 b, floatx4 c) {
  return __builtin_amdgcn_mfma_f32_16x16x32_bf16(a, b, c, 0, 0, 0);
}
// async global->LDS, 16B per lane; LDS dest = wave-uniform base + lane*16
#define DMA16(g, l)                                                              \
  __builtin_amdgcn_global_load_lds((const __attribute__((address_space(1))) void*)(g), \
                                   (__attribute__((address_space(3))) void*)(l), 16, 0, 0)

// ---------------- transpose+convert fp32 -> bf16 [C][R] (batch z) ----------------
__global__ __launch_bounds__(256) void k_cvtT(const float* __restrict__ src,
                                              ushort* __restrict__ dst, int R, int C) {
  __shared__ float tile[32][33];
  size_t sb = (size_t)blockIdx.z * R * C;
  const float* s = src + sb;
  ushort* d = dst + sb;
  int r0 = blockIdx.y * 32, c0 = blockIdx.x * 32;
  int tc = threadIdx.x & 31, tr = threadIdx.x >> 5;
#pragma unroll
  for (int i = 0; i < 4; i++)
    tile[tr + i * 8][tc] = s[(size_t)(r0 + tr + i * 8) * C + c0 + tc];
  __syncthreads();
#pragma unroll
  for (int i = 0; i < 4; i++) {
    int cc = tr + i * 8;
    d[(size_t)(c0 + cc) * R + r0 + tc] = f2bf(tile[tc][cc]);
  }
}

// ---------------- transpose+split fp32 -> hi/lo bf16 [C][R] ----------------
__global__ __launch_bounds__(256) void k_cvtT2(const float* __restrict__ src,
                                               ushort* __restrict__ dh,
                                               ushort* __restrict__ dl, int R, int C) {
  __shared__ float tile[32][33];
  int r0 = blockIdx.y * 32, c0 = blockIdx.x * 32;
  int tc = threadIdx.x & 31, tr = threadIdx.x >> 5;
#pragma unroll
  for (int i = 0; i < 4; i++)
    tile[tr + i * 8][tc] = src[(size_t)(r0 + tr + i * 8) * C + c0 + tc];
  __syncthreads();
#pragma unroll
  for (int i = 0; i < 4; i++) {
    int cc = tr + i * 8;
    float v = tile[tc][cc];
    ushort h = f2bf(v);
    dh[(size_t)(c0 + cc) * R + r0 + tc] = h;
    dl[(size_t)(c0 + cc) * R + r0 + tc] = f2bf(v - bf2f(h));
  }
}

// ---------------- RMSNorm fp32 -> hi/lo bf16 split ----------------
__global__ __launch_bounds__(256) void k_rmsnorm2(const float* __restrict__ x,
                                                  const float* __restrict__ g,
                                                  ushort* __restrict__ oh,
                                                  ushort* __restrict__ ol) {
  int row = blockIdx.x;
  int t = threadIdx.x;
  const float4* x4 = (const float4*)(x + (size_t)row * D_DIM);
  float4 v = x4[t];
  float ss = v.x * v.x + v.y * v.y + v.z * v.z + v.w * v.w;
#pragma unroll
  for (int off = 32; off; off >>= 1) ss += __shfl_xor(ss, off, 64);
  __shared__ float red[4];
  if ((t & 63) == 0) red[t >> 6] = ss;
  __syncthreads();
  float tot = red[0] + red[1] + red[2] + red[3];
  float sc = rsqrtf(tot * (1.0f / D_DIM) + 1e-6f);
  const float4* g4 = (const float4*)g;
  float4 gv = g4[t];
  float vals[4] = {v.x * gv.x * sc, v.y * gv.y * sc, v.z * gv.z * sc, v.w * gv.w * sc};
  ushort4v h4, l4;
#pragma unroll
  for (int i = 0; i < 4; i++) {
    ushort h = f2bf(vals[i]);
    h4[i] = h;
    l4[i] = f2bf(vals[i] - bf2f(h));
  }
  *(ushort4v*)(oh + (size_t)row * D_DIM + t * 4) = h4;
  *(ushort4v*)(ol + (size_t)row * D_DIM + t * 4) = l4;
}

// ------- split-bf16 emulated-fp32 MFMA GEMM, 3-buffer counted-vmcnt pipeline -------
// Block tile 64m x 128n, 4 waves, wave tile 32m x 64n (acc 32 regs).
__global__ __launch_bounds__(256) void k_sgemm(const ushort* __restrict__ Ahg,
                                               const ushort* __restrict__ Alg,
                                               const ushort* __restrict__ Bhg,
                                               const ushort* __restrict__ Blg,
                                               float* __restrict__ C,
                                               const float* __restrict__ res,
                                               int N, int K) {
  __shared__ __align__(16) ushort L[36864];  // 3 x 12288 (24 KB each)
  int tid = threadIdx.x;
  int m0 = blockIdx.y * 64, n0 = blockIdx.x * 128;
  int wave = tid >> 6, lane = tid & 63, quad = lane >> 4, l15 = lane & 15;
  int wm = (wave >> 1) * 32, wn = (wave & 1) * 64;
  floatx4 acc[2][4];
#pragma unroll
  for (int i = 0; i < 2; i++)
#pragma unroll
    for (int j = 0; j < 4; j++) acc[i][j] = (floatx4){0.f, 0.f, 0.f, 0.f};
  const ushort* src[6];
  int off[6];
  int srow = lane >> 2;
  int kc = ((lane & 3) ^ ((lane >> 3) & 3)) * 8;
#pragma unroll
  for (int j = 0; j < 6; j++) {
    int c = wave * 6 + j;
    if (c < 4) {
      src[j] = Ahg + (size_t)(m0 + c * 16 + srow) * K + kc;
      off[j] = c * 512;
    } else if (c < 8) {
      src[j] = Alg + (size_t)(m0 + (c - 4) * 16 + srow) * K + kc;
      off[j] = 2048 + (c - 4) * 512;
    } else if (c < 16) {
      src[j] = Bhg + (size_t)(n0 + (c - 8) * 16 + srow) * K + kc;
      off[j] = 4096 + (c - 8) * 512;
    } else {
      src[j] = Blg + (size_t)(n0 + (c - 16) * 16 + srow) * K + kc;
      off[j] = 8192 + (c - 16) * 512;
    }
  }
  auto stage = [&](ushort* Ld, int k0) {
#pragma unroll
    for (int j = 0; j < 6; j++) DMA16(src[j] + k0, Ld + off[j]);
  };
  auto compute = [&](const ushort* Ld) {
    const ushort* Ah = Ld;
    const ushort* Al = Ld + 2048;
    const ushort* Bh = Ld + 4096;
    const ushort* Bl = Ld + 8192;
    short8 ah[2], al[2], bh[4], bl[4];
#pragma unroll
    for (int mt = 0; mt < 2; mt++) {
      int ar = wm + mt * 16 + l15;
      int sw = (quad ^ ((ar >> 1) & 3)) * 8;
      ah[mt] = *(short8*)&Ah[ar * 32 + sw];
      al[mt] = *(short8*)&Al[ar * 32 + sw];
    }
#pragma unroll
    for (int nt = 0; nt < 4; nt++) {
      int br = wn + nt * 16 + l15;
      int sw = (quad ^ ((br >> 1) & 3)) * 8;
      bh[nt] = *(short8*)&Bh[br * 32 + sw];
      bl[nt] = *(short8*)&Bl[br * 32 + sw];
    }
#pragma unroll
    for (int mt = 0; mt < 2; mt++)
#pragma unroll
      for (int nt = 0; nt < 4; nt++) {
        acc[mt][nt] = mfma16(ah[mt], bh[nt], acc[mt][nt]);
        acc[mt][nt] = mfma16(ah[mt], bl[nt], acc[mt][nt]);
        acc[mt][nt] = mfma16(al[mt], bh[nt], acc[mt][nt]);
      }
  };
  int ntile = K >> 5;
  stage(L, 0);
  stage(L + 12288, 32);
  int cb = 0;
  for (int t = 0; t < ntile; t++) {
    if (t + 1 < ntile) { WAITCNT(6); } else { WAITCNT(0); }
    __builtin_amdgcn_s_barrier();
    __builtin_amdgcn_sched_barrier(0);
    if (t + 2 < ntile) {
      int sb = cb + 2; if (sb >= 3) sb -= 3;
      stage(L + sb * 12288, (t + 2) << 5);
    }
    compute(L + cb * 12288);
    if (++cb == 3) cb = 0;
  }
#pragma unroll
  for (int mt = 0; mt < 2; mt++) {
    int row = m0 + wm + mt * 16 + quad * 4;
#pragma unroll
    for (int nt2 = 0; nt2 < 4; nt2++) {
      int col = n0 + wn + nt2 * 16 + l15;
#pragma unroll
      for (int r = 0; r < 4; r++) {
        float v = acc[mt][nt2][r];
        if (res) v += res[(size_t)(row + r) * N + col];
        C[(size_t)(row + r) * N + col] = v;
      }
    }
  }
}

// ------- RoPE fp32 -> split-bf16: qkvf [T,1536] -> qhi/qlo [HQ][T][64], khi/klo [HKV][T][64] -------
__global__ __launch_bounds__(256) void k_rope_cvt(const float* __restrict__ qkvf,
                                                  ushort* __restrict__ qhi,
                                                  ushort* __restrict__ qlo,
                                                  ushort* __restrict__ khi,
                                                  ushort* __restrict__ klo) {
  int t = blockIdx.x;
  const float* row = qkvf + (size_t)t * 1536;
  for (int it = threadIdx.x; it < (HQn + HKVn) * 32; it += 256) {
    int hh = it >> 5, i = it & 31;
    float inv = powf(10000.0f, -(float)i / 32.0f);
    float ang = (float)t * inv;
    float c = cosf(ang), s = sinf(ang);
    const float* p;
    ushort *dh, *dl;
    size_t base;
    if (hh < HQn) {
      p = row + hh * 64;
      base = ((size_t)hh * T_LEN + t) * 64;
      dh = qhi; dl = qlo;
    } else {
      int h2 = hh - HQn;
      p = row + 1024 + h2 * 64;
      base = ((size_t)h2 * T_LEN + t) * 64;
      dh = khi; dl = klo;
    }
    float a = p[i], b = p[i + 32];
    float v0 = a * c - b * s;
    float v1 = b * c + a * s;
    ushort h0 = f2bf(v0);
    dh[base + i] = h0;
    dl[base + i] = f2bf(v0 - bf2f(h0));
    ushort h1 = f2bf(v1);
    dh[base + i + 32] = h1;
    dl[base + i + 32] = f2bf(v1 - bf2f(h1));
  }
}

// ------- V transpose fp32 -> split-bf16: qkvf v-part -> vbth/vbtl [HKV*64][T] -------
__global__ __launch_bounds__(256) void k_vT(const float* __restrict__ qkvf,
                                            ushort* __restrict__ vbth,
                                            ushort* __restrict__ vbtl) {
  __shared__ float tile[32][33];
  int t0 = blockIdx.x * 32;
  int dh = blockIdx.y;
  int col0 = 1280 + dh * 32;
  int tc = threadIdx.x & 31, tr = threadIdx.x >> 5;
#pragma unroll
  for (int i = 0; i < 4; i++)
    tile[tr + i * 8][tc] = qkvf[(size_t)(t0 + tr + i * 8) * 1536 + col0 + tc];
  __syncthreads();
#pragma unroll
  for (int i = 0; i < 4; i++) {
    int dd = tr + i * 8;
    float v = tile[tc][dd];
    ushort h = f2bf(v);
    size_t idx = (size_t)(dh * 32 + dd) * T_LEN + t0 + tc;
    vbth[idx] = h;
    vbtl[idx] = f2bf(v - bf2f(h));
  }
}

// ------- split-bf16 MFMA flash attention, DMA-staged K/V, balanced q-tile pairing -------
__global__ __launch_bounds__(256) void k_attn(const ushort* __restrict__ qhi,
                                              const ushort* __restrict__ qlo,
                                              const ushort* __restrict__ khi,
                                              const ushort* __restrict__ klo,
                                              const ushort* __restrict__ vbth,
                                              const ushort* __restrict__ vbtl,
                                              ushort* __restrict__ obh,
                                              ushort* __restrict__ obl) {
  __shared__ __align__(16) ushort Kh[4096], Kl[4096], Vh[4096], Vl[4096];
  __shared__ ushort Psh[4 * 16 * 72], Psl[4 * 16 * 72];
  int qh = blockIdx.y, kvh = qh >> 2;
  int tid = threadIdx.x, wave = tid >> 6, lane = tid & 63;
  int quad = lane >> 4, l15 = lane & 15;
  int sx = l15 >> 1;  // read-side swizzle (row>>1)&7 for rows nt*16+l15
  int rlb = lane >> 3;                      // staging: row-in-8
  int csb = (lane & 7) ^ (lane >> 4);       // staging: source chunk base
#pragma unroll 1
  for (int hf = 0; hf < 2; hf++) {
    int xt = hf ? (31 - (int)blockIdx.x) : (int)blockIdx.x;
    int r0 = xt * 64;
    const ushort* qbh_ = qhi + ((size_t)qh * T_LEN + r0 + wave * 16 + l15) * 64;
    const ushort* qbl_ = qlo + ((size_t)qh * T_LEN + r0 + wave * 16 + l15) * 64;
    short8 aqh0 = *(const short8*)&qbh_[quad * 8];
    short8 aqh1 = *(const short8*)&qbh_[32 + quad * 8];
    short8 aql0 = *(const short8*)&qbl_[quad * 8];
    short8 aql1 = *(const short8*)&qbl_[32 + quad * 8];
    floatx4 oacc[4];
#pragma unroll
    for (int nt = 0; nt < 4; nt++) oacc[nt] = (floatx4){0.f, 0.f, 0.f, 0.f};
    float mrun[4], lrun[4];
#pragma unroll
    for (int r = 0; r < 4; r++) { mrun[r] = -INFINITY; lrun[r] = 0.f; }
    for (int cc = 0; cc <= xt; cc++) {
      __syncthreads();  // all waves done reading previous tile
      if (wave < 2) {
        const ushort* G = (wave == 0) ? khi : klo;
        ushort* L = (wave == 0) ? Kh : Kl;
        size_t rbase = (size_t)kvh * T_LEN + cc * 64;
#pragma unroll
        for (int i = 0; i < 8; i++) {
          int ch = csb ^ ((i & 1) * 4);
          DMA16(G + (rbase + i * 8 + rlb) * 64 + ch * 8, L + i * 512);
        }
      } else {
        const ushort* G = (wave == 2) ? vbth : vbtl;
        ushort* L = (wave == 2) ? Vh : Vl;
#pragma unroll
        for (int i = 0; i < 8; i++) {
          int ch = csb ^ ((i & 1) * 4);
          DMA16(G + ((size_t)(kvh * 64 + i * 8 + rlb)) * T_LEN + cc * 64 + ch * 8,
                L + i * 512);
        }
      }
      __syncthreads();  // DMA landed (vmcnt drained by barrier)
      floatx4 s[4];
#pragma unroll
      for (int nt = 0; nt < 4; nt++) {
        int row = nt * 16 + l15;
        short8 bh0 = *(short8*)&Kh[row * 64 + (quad ^ sx) * 8];
        short8 bh1 = *(short8*)&Kh[row * 64 + ((4 + quad) ^ sx) * 8];
        short8 bl0 = *(short8*)&Kl[row * 64 + (quad ^ sx) * 8];
        short8 bl1 = *(short8*)&Kl[row * 64 + ((4 + quad) ^ sx) * 8];
        floatx4 z = (floatx4){0.f, 0.f, 0.f, 0.f};
        z = mfma16(aqh0, bh0, z);
        z = mfma16(aqh1, bh1, z);
        z = mfma16(aqh0, bl0, z);
        z = mfma16(aqh1, bl1, z);
        z = mfma16(aql0, bh0, z);
        z = mfma16(aql1, bh1, z);
        s[nt] = z;
      }
      int rowg0 = r0 + wave * 16 + quad * 4;
#pragma unroll
      for (int nt = 0; nt < 4; nt++) {
        int colg = cc * 64 + nt * 16 + l15;
#pragma unroll
        for (int r = 0; r < 4; r++) {
          float v = s[nt][r] * ATT_SCALE;
          s[nt][r] = (colg > rowg0 + r) ? -INFINITY : v;
        }
      }
      float mnew[4], alpha[4], psum[4];
#pragma unroll
      for (int r = 0; r < 4; r++) {
        float mx = fmaxf(fmaxf(s[0][r], s[1][r]), fmaxf(s[2][r], s[3][r]));
#pragma unroll
        for (int off = 1; off < 16; off <<= 1) mx = fmaxf(mx, __shfl_xor(mx, off, 64));
        mnew[r] = fmaxf(mrun[r], mx);
        psum[r] = 0.f;
      }
#pragma unroll
      for (int nt = 0; nt < 4; nt++)
#pragma unroll
        for (int r = 0; r < 4; r++) {
          float p = __expf(s[nt][r] - mnew[r]);
          s[nt][r] = p;
          psum[r] += p;
        }
#pragma unroll
      for (int r = 0; r < 4; r++) {
        float ps = psum[r];
#pragma unroll
        for (int off = 1; off < 16; off <<= 1) ps += __shfl_xor(ps, off, 64);
        alpha[r] = __expf(mrun[r] - mnew[r]);
        lrun[r] = lrun[r] * alpha[r] + ps;
        mrun[r] = mnew[r];
      }
#pragma unroll
      for (int nt = 0; nt < 4; nt++)
#pragma unroll
        for (int r = 0; r < 4; r++) oacc[nt][r] *= alpha[r];
#pragma unroll
      for (int nt = 0; nt < 4; nt++)
#pragma unroll
        for (int r = 0; r < 4; r++) {
          float p = s[nt][r];
          ushort ph = f2bf(p);
          Psh[wave * 1152 + (quad * 4 + r) * 72 + nt * 16 + l15] = ph;
          Psl[wave * 1152 + (quad * 4 + r) * 72 + nt * 16 + l15] = f2bf(p - bf2f(ph));
        }
      short8 aph0 = *(short8*)&Psh[wave * 1152 + l15 * 72 + quad * 8];
      short8 aph1 = *(short8*)&Psh[wave * 1152 + l15 * 72 + 32 + quad * 8];
      short8 apl0 = *(short8*)&Psl[wave * 1152 + l15 * 72 + quad * 8];
      short8 apl1 = *(short8*)&Psl[wave * 1152 + l15 * 72 + 32 + quad * 8];
#pragma unroll
      for (int nt = 0; nt < 4; nt++) {
        int row = nt * 16 + l15;
        short8 bvh0 = *(short8*)&Vh[row * 64 + (quad ^ sx) * 8];
        short8 bvh1 = *(short8*)&Vh[row * 64 + ((4 + quad) ^ sx) * 8];
        short8 bvl0 = *(short8*)&Vl[row * 64 + (quad ^ sx) * 8];
        short8 bvl1 = *(short8*)&Vl[row * 64 + ((4 + quad) ^ sx) * 8];
        oacc[nt] = mfma16(aph0, bvh0, oacc[nt]);
        oacc[nt] = mfma16(aph1, bvh1, oacc[nt]);
        oacc[nt] = mfma16(aph0, bvl0, oacc[nt]);
        oacc[nt] = mfma16(aph1, bvl1, oacc[nt]);
        oacc[nt] = mfma16(apl0, bvh0, oacc[nt]);
        oacc[nt] = mfma16(apl1, bvh1, oacc[nt]);
      }
    }
#pragma unroll
    for (int nt = 0; nt < 4; nt++)
#pragma unroll
      for (int r = 0; r < 4; r++) {
        int rowg = r0 + wave * 16 + quad * 4 + r;
        float v = oacc[nt][r] / lrun[r];
        ushort h = f2bf(v);
        size_t idx = (size_t)rowg * D_DIM + qh * 64 + nt * 16 + l15;
        obh[idx] = h;
        obl[idx] = f2bf(v - bf2f(h));
      }
  }
}

// ------- gate: fp32 rmsnorm+logits, hierarchical routing (block-level atomics) -------
__global__ __launch_bounds__(256) void k_gate(const float* __restrict__ x1,
                                              const float* __restrict__ g2,
                                              const float* __restrict__ gw,
                                              int* __restrict__ counts,
                                              int* __restrict__ ids,
                                              float* __restrict__ wts,
                                              float* __restrict__ load_sum) {
  __shared__ float lsum[NE];
  __shared__ int lcount[NE];
  __shared__ int lbase[NE];
  __shared__ int ltok[GATE_TPB * 2];
  __shared__ int lexp[GATE_TPB * 2];
  __shared__ float lwt[GATE_TPB * 2];
  int tid = threadIdx.x, wave = tid >> 6, lane = tid & 63;
  if (tid < NE) { lsum[tid] = 0.f; lcount[tid] = 0; }
  __syncthreads();
  int t0 = blockIdx.x * GATE_TPB;
#pragma unroll
  for (int tt = 0; tt < GATE_TPB / 4; tt++) {
    int tloc = tt * 4 + wave;
    int token = t0 + tloc;
    const float* xp = x1 + (size_t)token * D_DIM;
    float acc[NE] = {};
    float ss = 0.f;
    for (int d = lane; d < D_DIM; d += 64) {
      float xv = xp[d];
      ss += xv * xv;
      float hv = xv * g2[d];
#pragma unroll
      for (int e = 0; e < NE; e++) acc[e] += hv * gw[d * NE + e];
    }
#pragma unroll
    for (int off = 32; off; off >>= 1) ss += __shfl_xor(ss, off, 64);
#pragma unroll
    for (int e = 0; e < NE; e++)
#pragma unroll
      for (int off = 32; off; off >>= 1) acc[e] += __shfl_xor(acc[e], off, 64);
    if (lane == 0) {
      float sc = rsqrtf(ss * (1.0f / D_DIM) + 1e-6f);
      float mx = -1e30f;
#pragma unroll
      for (int e = 0; e < NE; e++) { acc[e] *= sc; mx = fmaxf(mx, acc[e]); }
      float p[NE], sum = 0.f;
#pragma unroll
      for (int e = 0; e < NE; e++) { p[e] = expf(acc[e] - mx); sum += p[e]; }
#pragma unroll
      for (int e = 0; e < NE; e++) p[e] /= sum;
      int i1 = 0;
#pragma unroll
      for (int e = 1; e < NE; e++) if (acc[e] > acc[i1]) i1 = e;
      int i2 = (i1 == 0) ? 1 : 0;
#pragma unroll
      for (int e = 0; e < NE; e++) if (e != i1 && acc[e] > acc[i2]) i2 = e;
      float denom = p[i1] + p[i2] + 1e-8f;
      int slot = tloc * 2;
      lexp[slot] = i1; ltok[slot] = token; lwt[slot] = p[i1] / denom;
      lexp[slot + 1] = i2; ltok[slot + 1] = token; lwt[slot + 1] = p[i2] / denom;
      atomicAdd(&lcount[i1], 1);
      atomicAdd(&lcount[i2], 1);
#pragma unroll
      for (int e = 0; e < NE; e++) atomicAdd(&lsum[e], p[e]);
    }
  }
  __syncthreads();
  if (tid < NE) {
    lbase[tid] = atomicAdd(&counts[tid], lcount[tid]);
    atomicAdd(&load_sum[tid], lsum[tid]);
    lcount[tid] = 0;
  }
  __syncthreads();
  if (tid < GATE_TPB * 2) {
    int e = lexp[tid];
    int off = atomicAdd(&lcount[e], 1);
    int pos = lbase[e] + off;
    ids[e * NTOK + pos] = ltok[tid];
    wts[e * NTOK + pos] = lwt[tid];
  }
}

__global__ void k_offsets(const int* __restrict__ counts, int* __restrict__ offsets) {
  if (threadIdx.x == 0 && blockIdx.x == 0) {
    int s = 0;
    for (int e = 0; e < NE; e++) { offsets[e] = s; s += counts[e]; }
  }
}

// ------- MoE gate/up bf16 MFMA GEMM, 2-phase dbuf + XCD panel-group swizzle -------
// 1D grid 5504 blocks. Swizzle: the 16 m-blocks sharing an (e,n0) weight panel are
// dispatched to ONE XCD; panel groups round-robin across XCDs (load-balanced).
// Block tile 128m x 64n; wave tile 64m x 32n of BOTH matrices (accg+accu = 64 regs).
__global__ __launch_bounds__(256) void k_moe_gateup(const ushort* __restrict__ h,
                                                    const ushort* __restrict__ wgT,
                                                    const ushort* __restrict__ wuT,
                                                    const int* __restrict__ ids,
                                                    const float* __restrict__ wts,
                                                    const int* __restrict__ counts,
                                                    const int* __restrict__ offsets,
                                                    ushort* __restrict__ act) {
  int p = blockIdx.x;
  int k8 = p & 7, q = p >> 3;          // q in [0,688)
  int G = (q >> 4) * 8 + k8;           // panel group in [0,344)
  int m = q & 15;
  int e = G / 43;
  int n = G - e * 43;
  int cnt = counts[e];
  int m0 = m * 128;
  if (m0 >= cnt) return;
  int n0 = n * 64;
  __shared__ __align__(16) ushort L0[8192], L1[8192];
  __shared__ int toks[128];
  __shared__ float wrow[128];
  int tid = threadIdx.x;
  if (tid < 128) {
    int mm = m0 + tid;
    toks[tid] = (mm < cnt) ? ids[e * NTOK + mm] : 0;
    wrow[tid] = (mm < cnt) ? wts[e * NTOK + mm] : 0.f;
  }
  __syncthreads();
  int wave = tid >> 6, lane = tid & 63, quad = lane >> 4, l15 = lane & 15;
  int wm = (wave >> 1) * 64, wn = (wave & 1) * 32;
  const ushort* Wg = wgT + (size_t)e * FF * D_DIM;
  const ushort* Wu = wuT + (size_t)e * FF * D_DIM;
  const ushort* src[4];
  int off[4];
  int srow = lane >> 2;
  int kc = ((lane & 3) ^ ((lane >> 3) & 3)) * 8;
#pragma unroll
  for (int j = 0; j < 4; j++) {
    int c = wave * 4 + j;
    if (c < 8) {
      src[j] = h + (size_t)toks[c * 16 + srow] * D_DIM + kc;
      off[j] = c * 512;
    } else if (c < 12) {
      src[j] = Wg + (size_t)(n0 + (c - 8) * 16 + srow) * D_DIM + kc;
      off[j] = 4096 + (c - 8) * 512;
    } else {
      src[j] = Wu + (size_t)(n0 + (c - 12) * 16 + srow) * D_DIM + kc;
      off[j] = 6144 + (c - 12) * 512;
    }
  }
  floatx4 accg[4][2], accu[4][2];
#pragma unroll
  for (int i = 0; i < 4; i++)
#pragma unroll
    for (int j = 0; j < 2; j++) {
      accg[i][j] = (floatx4){0.f, 0.f, 0.f, 0.f};
      accu[i][j] = (floatx4){0.f, 0.f, 0.f, 0.f};
    }
  auto stage = [&](ushort* Ld, int k0) {
#pragma unroll
    for (int j = 0; j < 4; j++) DMA16(src[j] + k0, Ld + off[j]);
  };
  auto compute = [&](const ushort* Ld) {
    const ushort* As = Ld;
    const ushort* Bg = Ld + 4096;
    const ushort* Bu = Ld + 6144;
    short8 aF[4], bgF[2], buF[2];
#pragma unroll
    for (int mt = 0; mt < 4; mt++) {
      int ar = wm + mt * 16 + l15;
      int sw = (quad ^ ((ar >> 1) & 3)) * 8;
      aF[mt] = *(short8*)&As[ar * 32 + sw];
    }
#pragma unroll
    for (int nt = 0; nt < 2; nt++) {
      int br = wn + nt * 16 + l15;
      int sw = (quad ^ ((br >> 1) & 3)) * 8;
      bgF[nt] = *(short8*)&Bg[br * 32 + sw];
      buF[nt] = *(short8*)&Bu[br * 32 + sw];
    }
#pragma unroll
    for (int mt = 0; mt < 4; mt++)
#pragma unroll
      for (int nt = 0; nt < 2; nt++) {
        accg[mt][nt] = mfma16(aF[mt], bgF[nt], accg[mt][nt]);
        accu[mt][nt] = mfma16(aF[mt], buF[nt], accu[mt][nt]);
      }
  };
  stage(L0, 0);
  __syncthreads();
  for (int t = 0; t < 32; t++) {
    if ((t & 1) == 0) {
      if (t + 1 < 32) stage(L1, (t + 1) << 5);
      compute(L0);
    } else {
      if (t + 1 < 32) stage(L0, (t + 1) << 5);
      compute(L1);
    }
    __syncthreads();
  }
  int aoff = offsets[e];
#pragma unroll
  for (int mt = 0; mt < 4; mt++) {
    int mrow = wm + mt * 16 + quad * 4;
#pragma unroll
    for (int nt = 0; nt < 2; nt++) {
      int col = n0 + wn + nt * 16 + l15;
#pragma unroll
      for (int r = 0; r < 4; r++) {
        int ml = mrow + r;
        if (m0 + ml < cnt) {
          float g = accg[mt][nt][r];
          float u = accu[mt][nt][r];
          float sil = g / (1.f + __expf(-g));
          act[(size_t)(aoff + m0 + ml) * FF + col] = f2bf(sil * u * wrow[ml]);
        }
      }
    }
  }
}

// ------- MoE down bf16 MFMA GEMM, 3-buffer pipeline, K-split x2, XCD swizzle -------
// 1D grid 2048 blocks; 16 m-blocks per (z,n0) weight panel pinned to one XCD.
__global__ __launch_bounds__(256) void k_moe_down(const ushort* __restrict__ act,
                                                  const ushort* __restrict__ wdT,
                                                  const int* __restrict__ ids,
                                                  const int* __restrict__ counts,
                                                  const int* __restrict__ offsets,
                                                  float* __restrict__ moe_acc) {
  int p = blockIdx.x;
  int k8 = p & 7, q = p >> 3;          // q in [0,256)
  int G = (q >> 4) * 8 + k8;           // [0,128)
  int m = q & 15;
  int z = G >> 3;                      // [0,16)
  int n = G & 7;
  int e = z & 7, kh = z >> 3;
  int cnt = counts[e];
  int m0 = m * 128;
  if (m0 >= cnt) return;
  int n0 = n * 128;
  __shared__ __align__(16) ushort L[24576];  // 3 x 8192
  __shared__ int toks[128];
  int tid = threadIdx.x;
  if (tid < 128) {
    int mm = m0 + tid;
    toks[tid] = (mm < cnt) ? ids[e * NTOK + mm] : 0;
  }
  __syncthreads();
  int wave = tid >> 6, lane = tid & 63, quad = lane >> 4, l15 = lane & 15;
  int wm = (wave >> 1) * 64, wn = (wave & 1) * 64;
  int aoff = offsets[e];
  const ushort* Wd = wdT + (size_t)e * D_DIM * FF;
  const ushort* src[4];
  int off[4];
  int srow = lane >> 2;
  int kc = ((lane & 3) ^ ((lane >> 3) & 3)) * 8;
#pragma unroll
  for (int j = 0; j < 4; j++) {
    int c = wave * 4 + j;
    if (c < 8) {
      src[j] = act + (size_t)(aoff + m0 + c * 16 + srow) * FF + kc;
      off[j] = c * 512;
    } else {
      src[j] = Wd + (size_t)(n0 + (c - 8) * 16 + srow) * FF + kc;
      off[j] = 4096 + (c - 8) * 512;
    }
  }
  floatx4 acc[4][4];
#pragma unroll
  for (int i = 0; i < 4; i++)
#pragma unroll
    for (int j = 0; j < 4; j++) acc[i][j] = (floatx4){0.f, 0.f, 0.f, 0.f};
  auto stage = [&](ushort* Ld, int k0) {
#pragma unroll
    for (int j = 0; j < 4; j++) DMA16(src[j] + k0, Ld + off[j]);
  };
  auto compute = [&](const ushort* Ld) {
    const ushort* As = Ld;
    const ushort* Bs = Ld + 4096;
    short8 aF[4], bF[4];
#pragma unroll
    for (int mt = 0; mt < 4; mt++) {
      int ar = wm + mt * 16 + l15;
      int sw = (quad ^ ((ar >> 1) & 3)) * 8;
      aF[mt] = *(short8*)&As[ar * 32 + sw];
    }
#pragma unroll
    for (int nt = 0; nt < 4; nt++) {
      int br = wn + nt * 16 + l15;
      int sw = (quad ^ ((br >> 1) & 3)) * 8;
      bF[nt] = *(short8*)&Bs[br * 32 + sw];
    }
#pragma unroll
    for (int mt = 0; mt < 4; mt++)
#pragma unroll
      for (int nt = 0; nt < 4; nt++) acc[mt][nt] = mfma16(aF[mt], bF[nt], acc[mt][nt]);
  };
  int kbeg = kh * 1376;
  stage(L, kbeg);
  stage(L + 8192, kbeg + 32);
  int cb = 0;
  for (int t = 0; t < 43; t++) {
    if (t + 1 < 43) { WAITCNT(4); } else { WAITCNT(0); }
    __builtin_amdgcn_s_barrier();
    __builtin_amdgcn_sched_barrier(0);
    if (t + 2 < 43) {
      int sb = cb + 2; if (sb >= 3) sb -= 3;
      stage(L + sb * 8192, kbeg + ((t + 2) << 5));
    }
    compute(L + cb * 8192);
    if (++cb == 3) cb = 0;
  }
#pragma unroll
  for (int mt = 0; mt < 4; mt++) {
    int mrow = wm + mt * 16 + quad * 4;
#pragma unroll
    for (int nt2 = 0; nt2 < 4; nt2++) {
      int col = n0 + wn + nt2 * 16 + l15;
#pragma unroll
      for (int r = 0; r < 4; r++) {
        int ml = mrow + r;
        if (m0 + ml < cnt)
          atomicAdd(&moe_acc[(size_t)toks[ml] * D_DIM + col], acc[mt][nt2][r]);
      }
    }
  }
}

__global__ __launch_bounds__(256) void k_add(const float* __restrict__ a,
                                             const float* __restrict__ b,
                                             float* __restrict__ o) {
  int i = blockIdx.x * 256 + threadIdx.x;
  float4 va = ((const float4*)a)[i];
  float4 vb = ((const float4*)b)[i];
  float4 vo;
  vo.x = va.x + vb.x; vo.y = va.y + vb.y; vo.z = va.z + vb.z; vo.w = va.w + vb.w;
  ((float4*)o)[i] = vo;
}

__global__ void k_aux(const int* __restrict__ counts, const float* __restrict__ load_sum,
                      float* __restrict__ out_aux) {
  if (threadIdx.x == 0 && blockIdx.x == 0) {
    float s = 0.f;
    for (int e = 0; e < NE; e++)
      s += ((float)counts[e] / (float)NSLOT) * (load_sum[e] / (float)NTOK);
    *out_aux = 0.01f * (float)NE * s;
  }
}

extern "C" void kernel_launch(void* const* d_in, const int* in_sizes, int n_in,
                              void* d_out, int out_size, void* d_ws, size_t ws_size,
                              hipStream_t stream) {
  const float* x = (const float*)d_in[0];
  const float* g1 = (const float*)d_in[1];
  const float* g2 = (const float*)d_in[2];
  const float* wq = (const float*)d_in[3];
  const float* wk = (const float*)d_in[4];
  const float* wv = (const float*)d_in[5];
  const float* wo = (const float*)d_in[6];
  const float* gate_w = (const float*)d_in[7];
  const float* we_gate = (const float*)d_in[8];
  const float* we_up = (const float*)d_in[9];
  const float* we_down = (const float*)d_in[10];
  float* out = (float*)d_out;

  char* w = (char*)d_ws;
  size_t o = 0;
  auto alloc = [&](size_t bytes) -> char* {
    char* p = w + o;
    o = (o + bytes + 255) & ~(size_t)255;
    return p;
  };
  ushort* h1h = (ushort*)alloc((size_t)NTOK * D_DIM * 2);
  ushort* h1l = (ushort*)alloc((size_t)NTOK * D_DIM * 2);
  float* qkvf = (float*)alloc((size_t)NTOK * 1536 * 4);
  ushort* qhi = (ushort*)alloc((size_t)HQn * T_LEN * 64 * 2);
  ushort* qlo = (ushort*)alloc((size_t)HQn * T_LEN * 64 * 2);
  ushort* khi = (ushort*)alloc((size_t)HKVn * T_LEN * 64 * 2);
  ushort* klo = (ushort*)alloc((size_t)HKVn * T_LEN * 64 * 2);
  ushort* vbth = (ushort*)alloc((size_t)HKVn * 64 * T_LEN * 2);
  ushort* vbtl = (ushort*)alloc((size_t)HKVn * 64 * T_LEN * 2);
  ushort* obh = (ushort*)alloc((size_t)NTOK * D_DIM * 2);
  ushort* obl = (ushort*)alloc((size_t)NTOK * D_DIM * 2);
  float* x1 = (float*)alloc((size_t)NTOK * D_DIM * 4);
  float* moe_acc = (float*)alloc((size_t)NTOK * D_DIM * 4);
  ushort* act = (ushort*)alloc((size_t)(NSLOT + 128) * FF * 2);
  ushort* qkvwTh = (ushort*)alloc((size_t)1536 * 1024 * 2);
  ushort* qkvwTl = (ushort*)alloc((size_t)1536 * 1024 * 2);
  ushort* woTh = (ushort*)alloc((size_t)1024 * 1024 * 2);
  ushort* woTl = (ushort*)alloc((size_t)1024 * 1024 * 2);
  ushort* h2h = (ushort*)alloc((size_t)NTOK * D_DIM * 2);
  ushort* h2l = (ushort*)alloc((size_t)NTOK * D_DIM * 2);
  ushort* wgT = (ushort*)alloc((size_t)NE * FF * D_DIM * 2);
  ushort* wuT = (ushort*)alloc((size_t)NE * FF * D_DIM * 2);
  ushort* wdT = (ushort*)alloc((size_t)NE * D_DIM * FF * 2);
  int* counts = (int*)alloc(NE * 4);
  int* offsets = (int*)alloc(NE * 4);
  float* load_sum = (float*)alloc(NE * 4);
  int* ids = (int*)alloc((size_t)NE * NTOK * 4);
  float* wts = (float*)alloc((size_t)NE * NTOK * 4);

  hipMemsetAsync(moe_acc, 0, (size_t)NTOK * D_DIM * 4, stream);
  hipMemsetAsync(counts, 0, 768, stream);  // counts+offsets+load_sum slots

  // weight transposes (hi/lo split for fp32-accurate attention path, bf16 for experts)
  k_cvtT2<<<dim3(32, 32), 256, 0, stream>>>(wq, qkvwTh, qkvwTl, 1024, 1024);
  k_cvtT2<<<dim3(8, 32), 256, 0, stream>>>(wk, qkvwTh + (size_t)1024 * 1024,
                                           qkvwTl + (size_t)1024 * 1024, 1024, 256);
  k_cvtT2<<<dim3(8, 32), 256, 0, stream>>>(wv, qkvwTh + (size_t)1280 * 1024,
                                           qkvwTl + (size_t)1280 * 1024, 1024, 256);
  k_cvtT2<<<dim3(32, 32), 256, 0, stream>>>(wo, woTh, woTl, 1024, 1024);
  k_cvtT<<<dim3(86, 32, 8), 256, 0, stream>>>(we_gate, wgT, 1024, 2752);
  k_cvtT<<<dim3(86, 32, 8), 256, 0, stream>>>(we_up, wuT, 1024, 2752);
  k_cvtT<<<dim3(32, 86, 8), 256, 0, stream>>>(we_down, wdT, 2752, 1024);

  // attention path (fp32-accurate via split-bf16 MFMA)
  k_rmsnorm2<<<NTOK, 256, 0, stream>>>(x, g1, h1h, h1l);
  k_sgemm<<<dim3(12, 32), 256, 0, stream>>>(h1h, h1l, qkvwTh, qkvwTl, qkvf, nullptr,
                                            1536, 1024);
  k_rope_cvt<<<T_LEN, 256, 0, stream>>>(qkvf, qhi, qlo, khi, klo);
  k_vT<<<dim3(64, 8), 256, 0, stream>>>(qkvf, vbth, vbtl);
  k_attn<<<dim3(16, 16), 256, 0, stream>>>(qhi, qlo, khi, klo, vbth, vbtl, obh, obl);
  k_sgemm<<<dim3(8, 32), 256, 0, stream>>>(obh, obl, woTh, woTl, x1, x, 1024, 1024);

  // moe
  k_rmsnorm2<<<NTOK, 256, 0, stream>>>(x1, g2, h2h, h2l);
  k_gate<<<NTOK / GATE_TPB, 256, 0, stream>>>(x1, g2, gate_w, counts, ids, wts, load_sum);
  k_offsets<<<1, 1, 0, stream>>>(counts, offsets);
  k_moe_gateup<<<5504, 256, 0, stream>>>(h2h, wgT, wuT, ids, wts, counts, offsets, act);
  k_moe_down<<<2048, 256, 0, stream>>>(act, wdT, ids, counts, offsets, moe_acc);
  k_add<<<(NTOK * D_DIM) / (256 * 4), 256, 0, stream>>>(x1, moe_acc, out);
  k_aux<<<1, 1, 0, stream>>>(counts, load_sum, out + (size_t)NTOK * D_DIM);
}